// Round 10
// baseline (2652.233 us; speedup 1.0000x reference)
//
#include <hip/hip_runtime.h>
#include <math.h>

typedef unsigned short u16;
typedef unsigned int   u32;

// Problem constants (GPT reference)
#define V_  32000
#define D_  512
#define H_  8
#define DH_ 64
#define L_  8
#define FF_ 2048
#define B_  2
#define T_  2048
#define M_  (B_*T_)   // 4096 token rows

typedef __attribute__((ext_vector_type(8))) short bf16x8;  // 8 bf16 = 4 VGPR
typedef __attribute__((ext_vector_type(4))) float f32x4;

#define PL_ 2097152    // elements per Q/K/V plane: B*H*T*DH = 16*2048*64
#define WL_ 3145728ull // weight-plane elements per layer (qkv+af+ff1+ff2)

// Split fp32 -> bf16 hi + lo. hi = truncate(x), lo = truncate(x - hi).
// 3-pass MFMA (hi*HI + lo*HI + hi*LO) reproduces fp32 GEMM to ~1e-4 abs.
__device__ inline void split_bf16(float x, u16& hi, u16& lo) {
    u32 u = __float_as_uint(x);
    hi = (u16)(u >> 16);
    float hif = __uint_as_float(u & 0xFFFF0000u);
    lo = (u16)(__float_as_uint(x - hif) >> 16);
}

// Async global->LDS, 16B per lane. LDS dest = wave-uniform base + lane*16
// (HW behavior, m104/m108); global src is per-lane.
__device__ inline void gload_lds16(const u16* g, u16* l) {
    __builtin_amdgcn_global_load_lds(
        (__attribute__((address_space(1))) void*)(void*)const_cast<u16*>(g),
        (__attribute__((address_space(3))) void*)(void*)l, 16, 0, 0);
}

// ---------------------------------------------------------------------------
// Embedding + positional encoding: h[row,d] = emb[x[row],d] + pe(t,d), fp32
// ---------------------------------------------------------------------------
__global__ void embed_pe_kernel(const int* __restrict__ x,
                                const float* __restrict__ emb,
                                float* __restrict__ h) {
    int row = blockIdx.x;          // 0..M_-1 ; row = b*T + t
    int t   = row % T_;
    int tok = x[row];
    const float* er = emb + (size_t)tok * D_;
    for (int d = threadIdx.x; d < D_; d += blockDim.x) {
        int i = d >> 1;
        float freq = expf((float)(2 * i) * (-9.210340371976184f / (float)D_));
        float ang  = (float)t * freq;
        float pe   = (d & 1) ? cosf(ang) : sinf(ang);
        h[(size_t)row * D_ + d] = er[d] + pe;
    }
}

// ---------------------------------------------------------------------------
// LayerNorm: one wave per row of D=512. fp32 in, split-bf16 planes out.
// ---------------------------------------------------------------------------
__global__ __launch_bounds__(64)
void layernorm_kernel(const float* __restrict__ xin,
                      const float* __restrict__ scale,
                      const float* __restrict__ bias,
                      u16* __restrict__ yhi, u16* __restrict__ ylo) {
    int row  = blockIdx.x;
    int lane = threadIdx.x;        // 0..63
    const float* xr = xin + (size_t)row * D_;
    float v[8];
    float s = 0.f;
#pragma unroll
    for (int i = 0; i < 8; i++) { v[i] = xr[i * 64 + lane]; s += v[i]; }
#pragma unroll
    for (int off = 32; off; off >>= 1) s += __shfl_xor(s, off, 64);
    float mu = s * (1.0f / D_);
    float var = 0.f;
#pragma unroll
    for (int i = 0; i < 8; i++) { float d0 = v[i] - mu; var += d0 * d0; }
#pragma unroll
    for (int off = 32; off; off >>= 1) var += __shfl_xor(var, off, 64);
    var *= (1.0f / D_);
    float r = rsqrtf(var + 1e-5f);
#pragma unroll
    for (int i = 0; i < 8; i++) {
        int d0 = i * 64 + lane;
        float val = (v[i] - mu) * r * scale[d0] + bias[d0];
        u16 hi, lo; split_bf16(val, hi, lo);
        yhi[(size_t)row * D_ + d0] = hi;
        ylo[(size_t)row * D_ + d0] = lo;
    }
}

// ---------------------------------------------------------------------------
// Weight transpose + bf16 split: W[K][N] fp32 -> Thi/Tlo [N][K] bf16 planes.
// Generic single-matrix version (used for fc_w).
// ---------------------------------------------------------------------------
__global__ __launch_bounds__(256)
void transpose_split_kernel(const float* __restrict__ W,
                            u16* __restrict__ Thi, u16* __restrict__ Tlo,
                            int K, int N) {
    __shared__ float tile[32][33];
    int n0 = blockIdx.x * 32, k0 = blockIdx.y * 32;
    int tx = threadIdx.x, ty = threadIdx.y;   // 32 x 8
#pragma unroll
    for (int i = 0; i < 4; i++) {
        int k = k0 + ty + i * 8;
        tile[ty + i * 8][tx] = W[(size_t)k * N + n0 + tx];   // coalesced in n
    }
    __syncthreads();
#pragma unroll
    for (int i = 0; i < 4; i++) {
        int n = n0 + ty + i * 8;
        float x = tile[tx][ty + i * 8];
        u16 hi, lo; split_bf16(x, hi, lo);
        Thi[(size_t)n * K + k0 + tx] = hi;                   // coalesced in k
        Tlo[(size_t)n * K + k0 + tx] = lo;
    }
}

// ---------------------------------------------------------------------------
// Fused weight transpose: 4 matrices per layer; blockIdx.y = layer index.
// All-layer mode launches grid (3072, 8) ONCE per forward (weights are
// input-only -> no dependency on the layer loop); fallback launches
// (3072, 1) per layer with per-layer base pointers (blockIdx.y = 0).
// ---------------------------------------------------------------------------
__global__ __launch_bounds__(256)
void transpose_split4_kernel(const float* __restrict__ Wq_, const float* __restrict__ Wa_,
                             const float* __restrict__ W1_, const float* __restrict__ W2_,
                             u16* __restrict__ Thi_, u16* __restrict__ Tlo_) {
    __shared__ float tile[32][33];
    const int l = blockIdx.y;
    const float* Wq = Wq_ + (size_t)l * D_ * 3 * D_;
    const float* Wa = Wa_ + (size_t)l * D_ * D_;
    const float* W1 = W1_ + (size_t)l * D_ * FF_;
    const float* W2 = W2_ + (size_t)l * FF_ * D_;
    u16* Thi = Thi_ + (size_t)l * WL_;
    u16* Tlo = Tlo_ + (size_t)l * WL_;

    int id = blockIdx.x;
    const float* W; u16 *thi, *tlo; int K, N, nt;
    if (id < 768)       { W = Wq; thi = Thi;           tlo = Tlo;           K = 512;  N = 1536; nt = 48; }
    else if (id < 1024) { W = Wa; thi = Thi + 786432;  tlo = Tlo + 786432;  K = 512;  N = 512;  nt = 16; id -= 768; }
    else if (id < 2048) { W = W1; thi = Thi + 1048576; tlo = Tlo + 1048576; K = 512;  N = 2048; nt = 64; id -= 1024; }
    else                { W = W2; thi = Thi + 2097152; tlo = Tlo + 2097152; K = 2048; N = 512;  nt = 16; id -= 2048; }
    int n0 = (id % nt) * 32, k0 = (id / nt) * 32;
    int tx = threadIdx.x & 31, ty = threadIdx.x >> 5;   // 32 x 8
#pragma unroll
    for (int i = 0; i < 4; i++) {
        int k = k0 + ty + i * 8;
        tile[ty + i * 8][tx] = W[(size_t)k * N + n0 + tx];
    }
    __syncthreads();
#pragma unroll
    for (int i = 0; i < 4; i++) {
        int n = n0 + ty + i * 8;
        float x = tile[tx][ty + i * 8];
        u16 hi, lo; split_bf16(x, hi, lo);
        thi[(size_t)n * K + k0 + tx] = hi;
        tlo[(size_t)n * K + k0 + tx] = lo;
    }
}

// ---------------------------------------------------------------------------
// MFMA GEMM, templated tile 32FM x 32FN x 64, 4 waves, split-bf16 3-pass.
// Round-2/5/6 proven structure: single-buffered LDS, {barrier; stage;
// barrier; compute} per K-step, global_load_lds staging with linear LDS
// dest + inverse-swizzled global source col; reads byte ^= (row&7)<<4.
// F_XCDM (vocab, round-6 proven BEST @410us): xcd = p&7 owns 4 m-tiles,
// n streams fastest within the chunk.
// F_QKV epilogue: head-separated split-bf16 Q,K [bh][t][64] and V
// transposed [bh][64][t] (feeds MFMA flash directly).
// ---------------------------------------------------------------------------
#define F_GELU  1
#define F_RES   2
#define F_SPLIT 4
#define F_QKV   8
#define F_XCDM  16

template<int FM, int FN>
__global__ __launch_bounds__(256, 2)
void mfma_gemm_t(const u16* __restrict__ Ahi, const u16* __restrict__ Alo,
                 const u16* __restrict__ Bhi, const u16* __restrict__ Blo,
                 const float* __restrict__ bias, const float* __restrict__ res,
                 float* __restrict__ C, u16* __restrict__ Chi, u16* __restrict__ Clo,
                 u16* __restrict__ qkvp, int N, int K, int flags) {
    constexpr int TBM = 32 * FM, TBN = 32 * FN;
    __shared__ __align__(16) u16 ldsA[2][TBM][64];
    __shared__ __align__(16) u16 ldsB[2][TBN][64];
    const int tid = threadIdx.x;

    // ---- block -> (m0, n0) ----
    int m0, n0;
    if (flags & F_XCDM) {
        // vocab: grid (250, 32) -> 8000 blocks; xcd owns m-tiles [4x, 4x+4)
        int p    = blockIdx.y * (int)gridDim.x + blockIdx.x;
        int xcd  = p & 7;
        int i    = p >> 3;              // 0..999 within XCD
        int mloc = i / 250;             // 0..3 (n fastest within chunk)
        m0 = (xcd * 4 + mloc) * TBM;
        n0 = (i - mloc * 250) * TBN;
    } else {
        m0 = blockIdx.y * TBM;
        n0 = blockIdx.x * TBN;
    }

    const int wave = tid >> 6;
    const int lane = tid & 63;
    const int wr   = (wave >> 1) * 16 * FM;
    const int wc   = (wave & 1) * 16 * FN;
    const int lr   = lane & 15;
    const int lk   = lane >> 4;

    const int srow = wave * 8 + (lane >> 3);
    const int scol = ((lane & 7) ^ (lane >> 3)) * 8;   // inverse read swizzle
    const u16* As0 = Ahi + (size_t)(m0 + srow) * K + scol;
    const u16* As1 = Alo + (size_t)(m0 + srow) * K + scol;
    const u16* Bs0 = Bhi + (size_t)(n0 + srow) * K + scol;
    const u16* Bs1 = Blo + (size_t)(n0 + srow) * K + scol;

    f32x4 acc[FM][FN] = {};

    for (int k0 = 0; k0 < K; k0 += 64) {
        __syncthreads();                 // previous tile's compute done
#pragma unroll
        for (int q = 0; q < FM; q++) {
            gload_lds16(As0 + (size_t)q * 32 * K + k0, &ldsA[0][q * 32 + wave * 8][0]);
            gload_lds16(As1 + (size_t)q * 32 * K + k0, &ldsA[1][q * 32 + wave * 8][0]);
        }
#pragma unroll
        for (int q = 0; q < FN; q++) {
            gload_lds16(Bs0 + (size_t)q * 32 * K + k0, &ldsB[0][q * 32 + wave * 8][0]);
            gload_lds16(Bs1 + (size_t)q * 32 * K + k0, &ldsB[1][q * 32 + wave * 8][0]);
        }
        __syncthreads();                 // drains vmcnt(0) before barrier
#pragma unroll
        for (int ks = 0; ks < 2; ks++) {
            bf16x8 ah[FM], al[FM], bh[FN], bl[FN];
            const int koff = ks * 64 + lk * 16;
#pragma unroll
            for (int f = 0; f < FM; f++) {
                int arow = wr + f * 16 + lr;
                int aoff = koff ^ ((arow & 7) << 4);
                ah[f] = *(const bf16x8*)((const char*)(&ldsA[0][arow][0]) + aoff);
                al[f] = *(const bf16x8*)((const char*)(&ldsA[1][arow][0]) + aoff);
            }
#pragma unroll
            for (int f = 0; f < FN; f++) {
                int brow = wc + f * 16 + lr;
                int boff = koff ^ ((brow & 7) << 4);
                bh[f] = *(const bf16x8*)((const char*)(&ldsB[0][brow][0]) + boff);
                bl[f] = *(const bf16x8*)((const char*)(&ldsB[1][brow][0]) + boff);
            }
#pragma unroll
            for (int mf = 0; mf < FM; mf++)
#pragma unroll
                for (int nf = 0; nf < FN; nf++) {
                    acc[mf][nf] = __builtin_amdgcn_mfma_f32_16x16x32_bf16(ah[mf], bh[nf], acc[mf][nf], 0, 0, 0);
                    acc[mf][nf] = __builtin_amdgcn_mfma_f32_16x16x32_bf16(al[mf], bh[nf], acc[mf][nf], 0, 0, 0);
                    acc[mf][nf] = __builtin_amdgcn_mfma_f32_16x16x32_bf16(ah[mf], bl[nf], acc[mf][nf], 0, 0, 0);
                }
        }
    }

    // ---- epilogue ----
#pragma unroll
    for (int mf = 0; mf < FM; mf++) {
#pragma unroll
        for (int nf = 0; nf < FN; nf++) {
            int col = n0 + wc + nf * 16 + lr;
            float bv = bias[col];
            float cv[4];
            int t0 = m0 + wr + mf * 16 + lk * 4;
#pragma unroll
            for (int r = 0; r < 4; r++) {
                float c = acc[mf][nf][r] + bv;
                if (flags & F_GELU) c = 0.5f * c * (1.0f + erff(c * 0.7071067811865476f));
                if (flags & F_RES)  c += res[(size_t)(t0 + r) * N + col];
                cv[r] = c;
            }
            if (flags & F_QKV) {
                // col -> (section, head, dh); row -> (b, t)
                int sect = col >> 9, hh = (col >> 6) & 7, dh = col & 63;
                int bb = t0 >> 11, tt = t0 & 2047;
                size_t bh = (size_t)bb * 8 + hh;
                if (sect == 2) {   // V transposed: [bh][dh][t], 4 t's packed
                    ushort4 h4, l4;
                    split_bf16(cv[0], h4.x, l4.x); split_bf16(cv[1], h4.y, l4.y);
                    split_bf16(cv[2], h4.z, l4.z); split_bf16(cv[3], h4.w, l4.w);
                    size_t vi = (bh * 64 + dh) * T_ + tt;
                    *(ushort4*)(qkvp + 4 * (size_t)PL_ + vi) = h4;
                    *(ushort4*)(qkvp + 5 * (size_t)PL_ + vi) = l4;
                } else {           // Q or K: [bh][t][dh]
                    u16* dst = qkvp + (size_t)sect * 2 * PL_;
#pragma unroll
                    for (int r = 0; r < 4; r++) {
                        u16 hi, lo; split_bf16(cv[r], hi, lo);
                        size_t qi = (bh * T_ + tt + r) * 64 + dh;
                        dst[qi] = hi;
                        dst[PL_ + qi] = lo;
                    }
                }
            } else if (flags & F_SPLIT) {
#pragma unroll
                for (int r = 0; r < 4; r++) {
                    u16 hi, lo; split_bf16(cv[r], hi, lo);
                    Chi[(size_t)(t0 + r) * N + col] = hi;
                    Clo[(size_t)(t0 + r) * N + col] = lo;
                }
            } else {
#pragma unroll
                for (int r = 0; r < 4; r++)
                    C[(size_t)(t0 + r) * N + col] = cv[r];
            }
        }
    }
}

// ---------------------------------------------------------------------------
// MFMA causal flash attention (round-6 proven body — best measured total).
// Block = (qt, bh); 4 waves, wave w owns q rows [w*16, +16) x all 64 keys.
// Serial {barrier; stage K/V; barrier; compute} per K-tile; Q staged once.
// Balanced mapping: ids u and u+256 get complementary qt (i, 31-i) so every
// CU's block pair sums to 33 K-tiles.
// NEW (T5): s_setprio(1) around the MFMA clusters — flash runs 2 independent
// blocks/CU at different phases (the m191-positive regime), so the scheduler
// can favor the MFMA-issuing wave over staging waves of the other block.
// ---------------------------------------------------------------------------
__global__ __launch_bounds__(256)
void flash_mfma_kernel(const u16* __restrict__ qkvp,
                       u16* __restrict__ ohi, u16* __restrict__ olo) {
    const u16* qhp = qkvp;
    const u16* qlp = qkvp + (size_t)PL_;
    const u16* khp = qkvp + 2 * (size_t)PL_;
    const u16* klp = qkvp + 3 * (size_t)PL_;
    const u16* vhp = qkvp + 4 * (size_t)PL_;
    const u16* vlp = qkvp + 5 * (size_t)PL_;

    __shared__ __align__(16) u16 Qs[2][64][64];
    __shared__ __align__(16) u16 Ks[2][64][64];
    __shared__ __align__(16) u16 Vs[2][64][64];
    __shared__ __align__(16) u16 Ps[64][64];

    // balanced (qt, bh) from flat id: u and u+256 -> (i, 31-i)
    const int u    = blockIdx.x;       // 0..511
    const int r0   = u & 255;
    const int bh   = r0 & 15;          // b*H + head
    const int i0   = r0 >> 4;          // 0..15
    const int qt   = (u >> 8) ? (31 - i0) : i0;

    const int tid = threadIdx.x;
    const int w = tid >> 6, lane = tid & 63;
    const int lr = lane & 15, lk = lane >> 4;

    const int srow = w * 8 + (lane >> 3);
    const int scol = ((lane & 7) ^ (lane >> 3)) * 8;

    // stage Q once (drained by first loop barrier pair)
    {
        size_t qb = ((size_t)bh * T_ + qt * 64 + srow) * 64 + scol;
#pragma unroll
        for (int q = 0; q < 2; q++) {
            gload_lds16(qhp + qb + (size_t)q * 32 * 64, &Qs[0][q * 32 + w * 8][0]);
            gload_lds16(qlp + qb + (size_t)q * 32 * 64, &Qs[1][q * 32 + w * 8][0]);
        }
    }

    f32x4 accO[4] = {};
    float lsum[4] = {0.f, 0.f, 0.f, 0.f};

    for (int kt = 0; kt <= qt; kt++) {
        __syncthreads();               // all waves done reading prev K/V/P
        size_t kb = ((size_t)bh * T_ + kt * 64 + srow) * 64 + scol;
        size_t vb = ((size_t)bh * 64 + srow) * T_ + (size_t)kt * 64 + scol;
#pragma unroll
        for (int q = 0; q < 2; q++) {
            gload_lds16(khp + kb + (size_t)q * 32 * 64, &Ks[0][q * 32 + w * 8][0]);
            gload_lds16(klp + kb + (size_t)q * 32 * 64, &Ks[1][q * 32 + w * 8][0]);
            gload_lds16(vhp + vb + (size_t)q * 32 * T_, &Vs[0][q * 32 + w * 8][0]);
            gload_lds16(vlp + vb + (size_t)q * 32 * T_, &Vs[1][q * 32 + w * 8][0]);
        }
        __syncthreads();               // staging drained (vmcnt 0)

        // ---- S = Q K^T, 3-pass: wave rows [w*16, +16), all 64 keys ----
        f32x4 accS[4] = {};
        __builtin_amdgcn_s_setprio(1);
#pragma unroll
        for (int ks = 0; ks < 2; ks++) {
            const int koff = ks * 64 + lk * 16;
            const int arow = w * 16 + lr;
            const int aoff = koff ^ ((arow & 7) << 4);
            bf16x8 qh = *(const bf16x8*)((const char*)(&Qs[0][arow][0]) + aoff);
            bf16x8 ql = *(const bf16x8*)((const char*)(&Qs[1][arow][0]) + aoff);
#pragma unroll
            for (int nf = 0; nf < 4; nf++) {
                int brow = nf * 16 + lr;
                int boff = koff ^ ((brow & 7) << 4);
                bf16x8 kh = *(const bf16x8*)((const char*)(&Ks[0][brow][0]) + boff);
                bf16x8 kl = *(const bf16x8*)((const char*)(&Ks[1][brow][0]) + boff);
                accS[nf] = __builtin_amdgcn_mfma_f32_16x16x32_bf16(qh, kh, accS[nf], 0, 0, 0);
                accS[nf] = __builtin_amdgcn_mfma_f32_16x16x32_bf16(ql, kh, accS[nf], 0, 0, 0);
                accS[nf] = __builtin_amdgcn_mfma_f32_16x16x32_bf16(qh, kl, accS[nf], 0, 0, 0);
            }
        }
        __builtin_amdgcn_s_setprio(0);

        // ---- mask + exp + P->bf16 LDS + row-sum partials ----
        const bool edge = (kt == qt);
#pragma unroll
        for (int nf = 0; nf < 4; nf++) {
            int keyl = nf * 16 + lr;
#pragma unroll
            for (int r = 0; r < 4; r++) {
                int rowl = lk * 4 + r;             // within wave's 16 rows
                float s = accS[nf][r] * 0.125f;
                float p = (!edge || keyl <= w * 16 + rowl) ? __expf(s) : 0.f;
                lsum[r] += p;
                u32 uu = __float_as_uint(p);
                u16 pb = (u16)((uu + 0x7FFF + ((uu >> 16) & 1)) >> 16);  // RNE
                int row = w * 16 + rowl;
                *(u16*)((char*)(&Ps[0][0]) + row * 128 + ((keyl * 2) ^ ((row & 7) << 4))) = pb;
            }
        }

        // ---- O += P V (2-pass over V planes). P rows are same-wave. ----
        __builtin_amdgcn_s_setprio(1);
#pragma unroll
        for (int kk = 0; kk < 2; kk++) {
            const int koff = kk * 64 + lk * 16;
            const int arow = w * 16 + lr;
            bf16x8 pa = *(const bf16x8*)((const char*)(&Ps[0][0]) + arow * 128
                                         + (koff ^ ((arow & 7) << 4)));
#pragma unroll
            for (int nf = 0; nf < 4; nf++) {
                int brow = nf * 16 + lr;
                int boff = koff ^ ((brow & 7) << 4);
                bf16x8 vh = *(const bf16x8*)((const char*)(&Vs[0][brow][0]) + boff);
                bf16x8 vl = *(const bf16x8*)((const char*)(&Vs[1][brow][0]) + boff);
                accO[nf] = __builtin_amdgcn_mfma_f32_16x16x32_bf16(pa, vh, accO[nf], 0, 0, 0);
                accO[nf] = __builtin_amdgcn_mfma_f32_16x16x32_bf16(pa, vl, accO[nf], 0, 0, 0);
            }
        }
        __builtin_amdgcn_s_setprio(0);
    }

    // ---- finish: reduce row sums over the 16-lane col group, write O ----
#pragma unroll
    for (int r = 0; r < 4; r++) {
        float v = lsum[r];
        v += __shfl_xor(v, 1, 64); v += __shfl_xor(v, 2, 64);
        v += __shfl_xor(v, 4, 64); v += __shfl_xor(v, 8, 64);
        lsum[r] = v;
    }
    const int b = bh >> 3, hd = bh & 7;
#pragma unroll
    for (int nf = 0; nf < 4; nf++) {
#pragma unroll
        for (int r = 0; r < 4; r++) {
            float val = accO[nf][r] / lsum[r];
            u16 hi, lo; split_bf16(val, hi, lo);
            size_t idx = ((size_t)(b * T_ + qt * 64 + w * 16 + lk * 4 + r)) * D_
                         + hd * 64 + nf * 16 + lr;
            ohi[idx] = hi;
            olo[idx] = lo;
        }
    }
}

// ---------------------------------------------------------------------------
extern "C" void kernel_launch(void* const* d_in, const int* in_sizes, int n_in,
                              void* d_out, int out_size, void* d_ws, size_t ws_size,
                              hipStream_t stream) {
    const int*   x    = (const int*)   d_in[0];
    const float* emb  = (const float*) d_in[1];
    const float* ln1s = (const float*) d_in[2];
    const float* ln1b = (const float*) d_in[3];
    const float* qkvw = (const float*) d_in[4];
    const float* qkvb = (const float*) d_in[5];
    const float* afw  = (const float*) d_in[6];
    const float* afb  = (const float*) d_in[7];
    const float* ln2s = (const float*) d_in[8];
    const float* ln2b = (const float*) d_in[9];
    const float* fw1  = (const float*) d_in[10];
    const float* fb1  = (const float*) d_in[11];
    const float* fw2  = (const float*) d_in[12];
    const float* fb2  = (const float*) d_in[13];
    const float* lnfs = (const float*) d_in[14];
    const float* lnfb = (const float*) d_in[15];
    const float* fcw  = (const float*) d_in[16];
    const float* fcb  = (const float*) d_in[17];
    float* out = (float*)d_out;

    // Workspace: activations 50.3 MB, then weight planes.
    //  all-mode  (ws >= ~217 MB): Whi/Wlo each hold 8 per-layer slots (WL_
    //    elements each) + fc slot -> ONE transpose launch per forward.
    //  fallback (ws >= ~116 MB): single per-layer slot reused (round-9 layout).
    float* h     = (float*)d_ws;
    u16*   yhi   = (u16*)(h + (size_t)M_ * D_);
    u16*   ylo   = yhi   + (size_t)M_ * D_;
    u16*   atthi = ylo   + (size_t)M_ * D_;
    u16*   attlo = atthi + (size_t)M_ * D_;
    u16*   qkvp  = attlo + (size_t)M_ * D_;     // 6 * PL_ u16
    u16*   ffhi  = atthi;                        // alias (att+qkv dead in FFN)
    u16*   fflo  = ffhi + (size_t)M_ * FF_;
    u16*   Whi   = qkvp + 6 * (size_t)PL_;

    const size_t actBytes  = (size_t)((char*)Whi - (char*)d_ws);
    const size_t planeAll  = 8ull * WL_ + (size_t)D_ * V_;   // elements
    const size_t planeOne  = (size_t)D_ * V_;
    const bool   allmode   = ws_size >= actBytes + 2 * planeAll * sizeof(u16);
    const size_t plane     = allmode ? planeAll : planeOne;
    u16* Wlo  = Whi + plane;
    u16* WhiF = allmode ? (Whi + 8ull * WL_) : Whi;          // fc slot
    u16* WloF = allmode ? (Wlo + 8ull * WL_) : Wlo;
    const size_t lstride = allmode ? WL_ : 0;

    // per-layer offsets inside a weight slot (elements)
    const size_t oq = 0, oa = 786432, of1 = 1048576, of2 = 2097152;

    if (allmode) {
        // all 8 layers' weights transposed in ONE launch; fc upfront too
        transpose_split4_kernel<<<dim3(3072, 8), 256, 0, stream>>>(
            qkvw, afw, fw1, fw2, Whi, Wlo);
        transpose_split_kernel<<<dim3(V_ / 32, D_ / 32), dim3(32, 8), 0, stream>>>(
            fcw, WhiF, WloF, D_, V_);
    }

    embed_pe_kernel<<<M_, 128, 0, stream>>>(x, emb, h);

    for (int l = 0; l < L_; l++) {
        if (!allmode) {
            transpose_split4_kernel<<<dim3(3072, 1), 256, 0, stream>>>(
                qkvw + (size_t)l * D_ * 3 * D_, afw + (size_t)l * D_ * D_,
                fw1 + (size_t)l * D_ * FF_, fw2 + (size_t)l * FF_ * D_,
                Whi, Wlo);
        }
        u16* WhiL = Whi + (size_t)l * lstride;
        u16* WloL = Wlo + (size_t)l * lstride;

        layernorm_kernel<<<M_, 64, 0, stream>>>(h, ln1s + l * D_, ln1b + l * D_, yhi, ylo);
        // qkv: N=1536, 64^2 tiles, head-separated split output (F_QKV)
        mfma_gemm_t<2, 2><<<dim3(3 * D_ / 64, M_ / 64), 256, 0, stream>>>(
            yhi, ylo, WhiL + oq, WloL + oq, qkvb + l * 3 * D_,
            nullptr, nullptr, nullptr, nullptr, qkvp, 3 * D_, D_, F_QKV);
        // flash: 1-D grid, balanced (qt,bh) pairing (round-6 body + setprio)
        flash_mfma_kernel<<<(T_ / 64) * B_ * H_, 256, 0, stream>>>(qkvp, atthi, attlo);
        // attn-fc: N=512, 64^2 tiles -> 512 blocks
        mfma_gemm_t<2, 2><<<dim3(D_ / 64, M_ / 64), 256, 0, stream>>>(
            atthi, attlo, WhiL + oa, WloL + oa, afb + l * D_,
            h, h, nullptr, nullptr, nullptr, D_, D_, F_RES);
        layernorm_kernel<<<M_, 64, 0, stream>>>(h, ln2s + l * D_, ln2b + l * D_, yhi, ylo);
        // ff1: N=2048, 128^2 tiles -> 512 blocks
        mfma_gemm_t<4, 4><<<dim3(FF_ / 128, M_ / 128), 256, 0, stream>>>(
            yhi, ylo, WhiL + of1, WloL + of1, fb1 + l * FF_,
            nullptr, nullptr, ffhi, fflo, nullptr, FF_, D_, F_GELU | F_SPLIT);
        // ff2: N=512, K=2048 -> 512 blocks
        mfma_gemm_t<2, 2><<<dim3(D_ / 64, M_ / 64), 256, 0, stream>>>(
            ffhi, fflo, WhiL + of2, WloL + of2, fb2 + l * D_,
            h, h, nullptr, nullptr, nullptr, D_, FF_, F_RES);
    }

    if (!allmode) {
        transpose_split_kernel<<<dim3(V_ / 32, D_ / 32), dim3(32, 8), 0, stream>>>(
            fcw, WhiF, WloF, D_, V_);
    }
    layernorm_kernel<<<M_, 64, 0, stream>>>(h, lnfs, lnfb, yhi, ylo);
    // vocab: 128^2 tiles, round-6 F_XCDM mapping (best measured: 410 us)
    mfma_gemm_t<4, 4><<<dim3(V_ / 128, M_ / 128), 256, 0, stream>>>(
        yhi, ylo, WhiF, WloF, fcb, nullptr, out, nullptr, nullptr, nullptr,
        V_, D_, F_XCDM);
}

// Round 11
// 2592.037 us; speedup vs baseline: 1.0232x; 1.0232x over previous
//
#include <hip/hip_runtime.h>
#include <math.h>

typedef unsigned short u16;
typedef unsigned int   u32;

// Problem constants (GPT reference)
#define V_  32000
#define D_  512
#define H_  8
#define DH_ 64
#define L_  8
#define FF_ 2048
#define B_  2
#define T_  2048
#define M_  (B_*T_)   // 4096 token rows

typedef __attribute__((ext_vector_type(8))) short bf16x8;  // 8 bf16 = 4 VGPR
typedef __attribute__((ext_vector_type(4))) float f32x4;

#define PL_ 2097152   // elements per Q/K/V plane: B*H*T*DH = 16*2048*64

// Split fp32 -> bf16 hi + lo. hi = truncate(x), lo = truncate(x - hi).
// 3-pass MFMA (hi*HI + lo*HI + hi*LO) reproduces fp32 GEMM to ~1e-4 abs.
__device__ inline void split_bf16(float x, u16& hi, u16& lo) {
    u32 u = __float_as_uint(x);
    hi = (u16)(u >> 16);
    float hif = __uint_as_float(u & 0xFFFF0000u);
    lo = (u16)(__float_as_uint(x - hif) >> 16);
}

// Async global->LDS, 16B per lane. LDS dest = wave-uniform base + lane*16
// (HW behavior, m104/m108); global src is per-lane.
__device__ inline void gload_lds16(const u16* g, u16* l) {
    __builtin_amdgcn_global_load_lds(
        (__attribute__((address_space(1))) void*)(void*)const_cast<u16*>(g),
        (__attribute__((address_space(3))) void*)(void*)l, 16, 0, 0);
}

// ---------------------------------------------------------------------------
// Embedding + positional encoding: h[row,d] = emb[x[row],d] + pe(t,d), fp32
// ---------------------------------------------------------------------------
__global__ void embed_pe_kernel(const int* __restrict__ x,
                                const float* __restrict__ emb,
                                float* __restrict__ h) {
    int row = blockIdx.x;          // 0..M_-1 ; row = b*T + t
    int t   = row % T_;
    int tok = x[row];
    const float* er = emb + (size_t)tok * D_;
    for (int d = threadIdx.x; d < D_; d += blockDim.x) {
        int i = d >> 1;
        float freq = expf((float)(2 * i) * (-9.210340371976184f / (float)D_));
        float ang  = (float)t * freq;
        float pe   = (d & 1) ? cosf(ang) : sinf(ang);
        h[(size_t)row * D_ + d] = er[d] + pe;
    }
}

// ---------------------------------------------------------------------------
// LayerNorm: one wave per row of D=512, 8 waves per block (512 threads).
// ROUND-11: regrouped from 4096 single-wave blocks to 512 8-wave blocks —
// identical per-wave math (shfl width 64 is per-wave), 8x fewer blocks
// through the command processor per launch (17 LN launches/forward).
// fp32 in, split-bf16 planes out.
// ---------------------------------------------------------------------------
__global__ __launch_bounds__(512)
void layernorm_kernel(const float* __restrict__ xin,
                      const float* __restrict__ scale,
                      const float* __restrict__ bias,
                      u16* __restrict__ yhi, u16* __restrict__ ylo) {
    int row  = blockIdx.x * 8 + (threadIdx.x >> 6);
    int lane = threadIdx.x & 63;   // 0..63
    const float* xr = xin + (size_t)row * D_;
    float v[8];
    float s = 0.f;
#pragma unroll
    for (int i = 0; i < 8; i++) { v[i] = xr[i * 64 + lane]; s += v[i]; }
#pragma unroll
    for (int off = 32; off; off >>= 1) s += __shfl_xor(s, off, 64);
    float mu = s * (1.0f / D_);
    float var = 0.f;
#pragma unroll
    for (int i = 0; i < 8; i++) { float d0 = v[i] - mu; var += d0 * d0; }
#pragma unroll
    for (int off = 32; off; off >>= 1) var += __shfl_xor(var, off, 64);
    var *= (1.0f / D_);
    float r = rsqrtf(var + 1e-5f);
#pragma unroll
    for (int i = 0; i < 8; i++) {
        int d0 = i * 64 + lane;
        float val = (v[i] - mu) * r * scale[d0] + bias[d0];
        u16 hi, lo; split_bf16(val, hi, lo);
        yhi[(size_t)row * D_ + d0] = hi;
        ylo[(size_t)row * D_ + d0] = lo;
    }
}

// ---------------------------------------------------------------------------
// Weight transpose + bf16 split: W[K][N] fp32 -> Thi/Tlo [N][K] bf16 planes.
// Generic single-matrix version (used for fc_w).
// ---------------------------------------------------------------------------
__global__ __launch_bounds__(256)
void transpose_split_kernel(const float* __restrict__ W,
                            u16* __restrict__ Thi, u16* __restrict__ Tlo,
                            int K, int N) {
    __shared__ float tile[32][33];
    int n0 = blockIdx.x * 32, k0 = blockIdx.y * 32;
    int tx = threadIdx.x, ty = threadIdx.y;   // 32 x 8
#pragma unroll
    for (int i = 0; i < 4; i++) {
        int k = k0 + ty + i * 8;
        tile[ty + i * 8][tx] = W[(size_t)k * N + n0 + tx];   // coalesced in n
    }
    __syncthreads();
#pragma unroll
    for (int i = 0; i < 4; i++) {
        int n = n0 + ty + i * 8;
        float x = tile[tx][ty + i * 8];
        u16 hi, lo; split_bf16(x, hi, lo);
        Thi[(size_t)n * K + k0 + tx] = hi;                   // coalesced in k
        Tlo[(size_t)n * K + k0 + tx] = lo;
    }
}

// ---------------------------------------------------------------------------
// Fused per-layer transpose: all 4 weight matrices in one launch (round-6
// proven: per-layer launch keeps the hot weight slot L2/L3-warm for the
// immediately-following GEMMs; the all-layer hoist REGRESSED in round 10).
// ---------------------------------------------------------------------------
__global__ __launch_bounds__(256)
void transpose_split4_kernel(const float* __restrict__ Wq, const float* __restrict__ Wa,
                             const float* __restrict__ W1, const float* __restrict__ W2,
                             u16* __restrict__ Thi, u16* __restrict__ Tlo) {
    __shared__ float tile[32][33];
    int id = blockIdx.x;
    const float* W; u16 *thi, *tlo; int K, N, nt;
    if (id < 768)       { W = Wq; thi = Thi;           tlo = Tlo;           K = 512;  N = 1536; nt = 48; }
    else if (id < 1024) { W = Wa; thi = Thi + 786432;  tlo = Tlo + 786432;  K = 512;  N = 512;  nt = 16; id -= 768; }
    else if (id < 2048) { W = W1; thi = Thi + 1048576; tlo = Tlo + 1048576; K = 512;  N = 2048; nt = 64; id -= 1024; }
    else                { W = W2; thi = Thi + 2097152; tlo = Tlo + 2097152; K = 2048; N = 512;  nt = 16; id -= 2048; }
    int n0 = (id % nt) * 32, k0 = (id / nt) * 32;
    int tx = threadIdx.x & 31, ty = threadIdx.x >> 5;   // 32 x 8
#pragma unroll
    for (int i = 0; i < 4; i++) {
        int k = k0 + ty + i * 8;
        tile[ty + i * 8][tx] = W[(size_t)k * N + n0 + tx];
    }
    __syncthreads();
#pragma unroll
    for (int i = 0; i < 4; i++) {
        int n = n0 + ty + i * 8;
        float x = tile[tx][ty + i * 8];
        u16 hi, lo; split_bf16(x, hi, lo);
        thi[(size_t)n * K + k0 + tx] = hi;
        tlo[(size_t)n * K + k0 + tx] = lo;
    }
}

// ---------------------------------------------------------------------------
// MFMA GEMM, templated tile 32FM x 32FN x 64, 4 waves, split-bf16 3-pass.
// Round-2/5/6 proven structure: single-buffered LDS, {barrier; stage;
// barrier; compute} per K-step, global_load_lds staging with linear LDS
// dest + inverse-swizzled global source col; reads byte ^= (row&7)<<4.
// F_XCDM (vocab, round-6 proven BEST @410us): xcd = p&7 owns 4 m-tiles,
// n streams fastest within the chunk.
// F_QKV epilogue: head-separated split-bf16 Q,K [bh][t][64] and V
// transposed [bh][64][t] (feeds MFMA flash directly).
// ---------------------------------------------------------------------------
#define F_GELU  1
#define F_RES   2
#define F_SPLIT 4
#define F_QKV   8
#define F_XCDM  16

template<int FM, int FN>
__global__ __launch_bounds__(256, 2)
void mfma_gemm_t(const u16* __restrict__ Ahi, const u16* __restrict__ Alo,
                 const u16* __restrict__ Bhi, const u16* __restrict__ Blo,
                 const float* __restrict__ bias, const float* __restrict__ res,
                 float* __restrict__ C, u16* __restrict__ Chi, u16* __restrict__ Clo,
                 u16* __restrict__ qkvp, int N, int K, int flags) {
    constexpr int TBM = 32 * FM, TBN = 32 * FN;
    __shared__ __align__(16) u16 ldsA[2][TBM][64];
    __shared__ __align__(16) u16 ldsB[2][TBN][64];
    const int tid = threadIdx.x;

    // ---- block -> (m0, n0) ----
    int m0, n0;
    if (flags & F_XCDM) {
        // vocab: grid (250, 32) -> 8000 blocks; xcd owns m-tiles [4x, 4x+4)
        int p    = blockIdx.y * (int)gridDim.x + blockIdx.x;
        int xcd  = p & 7;
        int i    = p >> 3;              // 0..999 within XCD
        int mloc = i / 250;             // 0..3 (n fastest within chunk)
        m0 = (xcd * 4 + mloc) * TBM;
        n0 = (i - mloc * 250) * TBN;
    } else {
        m0 = blockIdx.y * TBM;
        n0 = blockIdx.x * TBN;
    }

    const int wave = tid >> 6;
    const int lane = tid & 63;
    const int wr   = (wave >> 1) * 16 * FM;
    const int wc   = (wave & 1) * 16 * FN;
    const int lr   = lane & 15;
    const int lk   = lane >> 4;

    const int srow = wave * 8 + (lane >> 3);
    const int scol = ((lane & 7) ^ (lane >> 3)) * 8;   // inverse read swizzle
    const u16* As0 = Ahi + (size_t)(m0 + srow) * K + scol;
    const u16* As1 = Alo + (size_t)(m0 + srow) * K + scol;
    const u16* Bs0 = Bhi + (size_t)(n0 + srow) * K + scol;
    const u16* Bs1 = Blo + (size_t)(n0 + srow) * K + scol;

    f32x4 acc[FM][FN] = {};

    for (int k0 = 0; k0 < K; k0 += 64) {
        __syncthreads();                 // previous tile's compute done
#pragma unroll
        for (int q = 0; q < FM; q++) {
            gload_lds16(As0 + (size_t)q * 32 * K + k0, &ldsA[0][q * 32 + wave * 8][0]);
            gload_lds16(As1 + (size_t)q * 32 * K + k0, &ldsA[1][q * 32 + wave * 8][0]);
        }
#pragma unroll
        for (int q = 0; q < FN; q++) {
            gload_lds16(Bs0 + (size_t)q * 32 * K + k0, &ldsB[0][q * 32 + wave * 8][0]);
            gload_lds16(Bs1 + (size_t)q * 32 * K + k0, &ldsB[1][q * 32 + wave * 8][0]);
        }
        __syncthreads();                 // drains vmcnt(0) before barrier
#pragma unroll
        for (int ks = 0; ks < 2; ks++) {
            bf16x8 ah[FM], al[FM], bh[FN], bl[FN];
            const int koff = ks * 64 + lk * 16;
#pragma unroll
            for (int f = 0; f < FM; f++) {
                int arow = wr + f * 16 + lr;
                int aoff = koff ^ ((arow & 7) << 4);
                ah[f] = *(const bf16x8*)((const char*)(&ldsA[0][arow][0]) + aoff);
                al[f] = *(const bf16x8*)((const char*)(&ldsA[1][arow][0]) + aoff);
            }
#pragma unroll
            for (int f = 0; f < FN; f++) {
                int brow = wc + f * 16 + lr;
                int boff = koff ^ ((brow & 7) << 4);
                bh[f] = *(const bf16x8*)((const char*)(&ldsB[0][brow][0]) + boff);
                bl[f] = *(const bf16x8*)((const char*)(&ldsB[1][brow][0]) + boff);
            }
#pragma unroll
            for (int mf = 0; mf < FM; mf++)
#pragma unroll
                for (int nf = 0; nf < FN; nf++) {
                    acc[mf][nf] = __builtin_amdgcn_mfma_f32_16x16x32_bf16(ah[mf], bh[nf], acc[mf][nf], 0, 0, 0);
                    acc[mf][nf] = __builtin_amdgcn_mfma_f32_16x16x32_bf16(al[mf], bh[nf], acc[mf][nf], 0, 0, 0);
                    acc[mf][nf] = __builtin_amdgcn_mfma_f32_16x16x32_bf16(ah[mf], bl[nf], acc[mf][nf], 0, 0, 0);
                }
        }
    }

    // ---- epilogue ----
#pragma unroll
    for (int mf = 0; mf < FM; mf++) {
#pragma unroll
        for (int nf = 0; nf < FN; nf++) {
            int col = n0 + wc + nf * 16 + lr;
            float bv = bias[col];
            float cv[4];
            int t0 = m0 + wr + mf * 16 + lk * 4;
#pragma unroll
            for (int r = 0; r < 4; r++) {
                float c = acc[mf][nf][r] + bv;
                if (flags & F_GELU) c = 0.5f * c * (1.0f + erff(c * 0.7071067811865476f));
                if (flags & F_RES)  c += res[(size_t)(t0 + r) * N + col];
                cv[r] = c;
            }
            if (flags & F_QKV) {
                // col -> (section, head, dh); row -> (b, t)
                int sect = col >> 9, hh = (col >> 6) & 7, dh = col & 63;
                int bb = t0 >> 11, tt = t0 & 2047;
                size_t bh = (size_t)bb * 8 + hh;
                if (sect == 2) {   // V transposed: [bh][dh][t], 4 t's packed
                    ushort4 h4, l4;
                    split_bf16(cv[0], h4.x, l4.x); split_bf16(cv[1], h4.y, l4.y);
                    split_bf16(cv[2], h4.z, l4.z); split_bf16(cv[3], h4.w, l4.w);
                    size_t vi = (bh * 64 + dh) * T_ + tt;
                    *(ushort4*)(qkvp + 4 * (size_t)PL_ + vi) = h4;
                    *(ushort4*)(qkvp + 5 * (size_t)PL_ + vi) = l4;
                } else {           // Q or K: [bh][t][dh]
                    u16* dst = qkvp + (size_t)sect * 2 * PL_;
#pragma unroll
                    for (int r = 0; r < 4; r++) {
                        u16 hi, lo; split_bf16(cv[r], hi, lo);
                        size_t qi = (bh * T_ + tt + r) * 64 + dh;
                        dst[qi] = hi;
                        dst[PL_ + qi] = lo;
                    }
                }
            } else if (flags & F_SPLIT) {
#pragma unroll
                for (int r = 0; r < 4; r++) {
                    u16 hi, lo; split_bf16(cv[r], hi, lo);
                    Chi[(size_t)(t0 + r) * N + col] = hi;
                    Clo[(size_t)(t0 + r) * N + col] = lo;
                }
            } else {
#pragma unroll
                for (int r = 0; r < 4; r++)
                    C[(size_t)(t0 + r) * N + col] = cv[r];
            }
        }
    }
}

// ---------------------------------------------------------------------------
// MFMA causal flash attention (round-6 proven body — best measured total;
// setprio REMOVED: round-10 A/B showed it regresses this barrier-locked
// structure, consistent with m190).
// Block = (qt, bh); 4 waves, wave w owns q rows [w*16, +16) x all 64 keys.
// Serial {barrier; stage K/V; barrier; compute} per K-tile; Q staged once.
// Balanced mapping: ids u and u+256 get complementary qt (i, 31-i) so every
// CU's block pair sums to 33 K-tiles.
// ---------------------------------------------------------------------------
__global__ __launch_bounds__(256)
void flash_mfma_kernel(const u16* __restrict__ qkvp,
                       u16* __restrict__ ohi, u16* __restrict__ olo) {
    const u16* qhp = qkvp;
    const u16* qlp = qkvp + (size_t)PL_;
    const u16* khp = qkvp + 2 * (size_t)PL_;
    const u16* klp = qkvp + 3 * (size_t)PL_;
    const u16* vhp = qkvp + 4 * (size_t)PL_;
    const u16* vlp = qkvp + 5 * (size_t)PL_;

    __shared__ __align__(16) u16 Qs[2][64][64];
    __shared__ __align__(16) u16 Ks[2][64][64];
    __shared__ __align__(16) u16 Vs[2][64][64];
    __shared__ __align__(16) u16 Ps[64][64];

    // balanced (qt, bh) from flat id: u and u+256 -> (i, 31-i)
    const int u    = blockIdx.x;       // 0..511
    const int r0   = u & 255;
    const int bh   = r0 & 15;          // b*H + head
    const int i0   = r0 >> 4;          // 0..15
    const int qt   = (u >> 8) ? (31 - i0) : i0;

    const int tid = threadIdx.x;
    const int w = tid >> 6, lane = tid & 63;
    const int lr = lane & 15, lk = lane >> 4;

    const int srow = w * 8 + (lane >> 3);
    const int scol = ((lane & 7) ^ (lane >> 3)) * 8;

    // stage Q once (drained by first loop barrier pair)
    {
        size_t qb = ((size_t)bh * T_ + qt * 64 + srow) * 64 + scol;
#pragma unroll
        for (int q = 0; q < 2; q++) {
            gload_lds16(qhp + qb + (size_t)q * 32 * 64, &Qs[0][q * 32 + w * 8][0]);
            gload_lds16(qlp + qb + (size_t)q * 32 * 64, &Qs[1][q * 32 + w * 8][0]);
        }
    }

    f32x4 accO[4] = {};
    float lsum[4] = {0.f, 0.f, 0.f, 0.f};

    for (int kt = 0; kt <= qt; kt++) {
        __syncthreads();               // all waves done reading prev K/V/P
        size_t kb = ((size_t)bh * T_ + kt * 64 + srow) * 64 + scol;
        size_t vb = ((size_t)bh * 64 + srow) * T_ + (size_t)kt * 64 + scol;
#pragma unroll
        for (int q = 0; q < 2; q++) {
            gload_lds16(khp + kb + (size_t)q * 32 * 64, &Ks[0][q * 32 + w * 8][0]);
            gload_lds16(klp + kb + (size_t)q * 32 * 64, &Ks[1][q * 32 + w * 8][0]);
            gload_lds16(vhp + vb + (size_t)q * 32 * T_, &Vs[0][q * 32 + w * 8][0]);
            gload_lds16(vlp + vb + (size_t)q * 32 * T_, &Vs[1][q * 32 + w * 8][0]);
        }
        __syncthreads();               // staging drained (vmcnt 0)

        // ---- S = Q K^T, 3-pass: wave rows [w*16, +16), all 64 keys ----
        f32x4 accS[4] = {};
#pragma unroll
        for (int ks = 0; ks < 2; ks++) {
            const int koff = ks * 64 + lk * 16;
            const int arow = w * 16 + lr;
            const int aoff = koff ^ ((arow & 7) << 4);
            bf16x8 qh = *(const bf16x8*)((const char*)(&Qs[0][arow][0]) + aoff);
            bf16x8 ql = *(const bf16x8*)((const char*)(&Qs[1][arow][0]) + aoff);
#pragma unroll
            for (int nf = 0; nf < 4; nf++) {
                int brow = nf * 16 + lr;
                int boff = koff ^ ((brow & 7) << 4);
                bf16x8 kh = *(const bf16x8*)((const char*)(&Ks[0][brow][0]) + boff);
                bf16x8 kl = *(const bf16x8*)((const char*)(&Ks[1][brow][0]) + boff);
                accS[nf] = __builtin_amdgcn_mfma_f32_16x16x32_bf16(qh, kh, accS[nf], 0, 0, 0);
                accS[nf] = __builtin_amdgcn_mfma_f32_16x16x32_bf16(ql, kh, accS[nf], 0, 0, 0);
                accS[nf] = __builtin_amdgcn_mfma_f32_16x16x32_bf16(qh, kl, accS[nf], 0, 0, 0);
            }
        }

        // ---- mask + exp + P->bf16 LDS + row-sum partials ----
        const bool edge = (kt == qt);
#pragma unroll
        for (int nf = 0; nf < 4; nf++) {
            int keyl = nf * 16 + lr;
#pragma unroll
            for (int r = 0; r < 4; r++) {
                int rowl = lk * 4 + r;             // within wave's 16 rows
                float s = accS[nf][r] * 0.125f;
                float p = (!edge || keyl <= w * 16 + rowl) ? __expf(s) : 0.f;
                lsum[r] += p;
                u32 uu = __float_as_uint(p);
                u16 pb = (u16)((uu + 0x7FFF + ((uu >> 16) & 1)) >> 16);  // RNE
                int row = w * 16 + rowl;
                *(u16*)((char*)(&Ps[0][0]) + row * 128 + ((keyl * 2) ^ ((row & 7) << 4))) = pb;
            }
        }

        // ---- O += P V (2-pass over V planes). P rows are same-wave. ----
#pragma unroll
        for (int kk = 0; kk < 2; kk++) {
            const int koff = kk * 64 + lk * 16;
            const int arow = w * 16 + lr;
            bf16x8 pa = *(const bf16x8*)((const char*)(&Ps[0][0]) + arow * 128
                                         + (koff ^ ((arow & 7) << 4)));
#pragma unroll
            for (int nf = 0; nf < 4; nf++) {
                int brow = nf * 16 + lr;
                int boff = koff ^ ((brow & 7) << 4);
                bf16x8 vh = *(const bf16x8*)((const char*)(&Vs[0][brow][0]) + boff);
                bf16x8 vl = *(const bf16x8*)((const char*)(&Vs[1][brow][0]) + boff);
                accO[nf] = __builtin_amdgcn_mfma_f32_16x16x32_bf16(pa, vh, accO[nf], 0, 0, 0);
                accO[nf] = __builtin_amdgcn_mfma_f32_16x16x32_bf16(pa, vl, accO[nf], 0, 0, 0);
            }
        }
    }

    // ---- finish: reduce row sums over the 16-lane col group, write O ----
#pragma unroll
    for (int r = 0; r < 4; r++) {
        float v = lsum[r];
        v += __shfl_xor(v, 1, 64); v += __shfl_xor(v, 2, 64);
        v += __shfl_xor(v, 4, 64); v += __shfl_xor(v, 8, 64);
        lsum[r] = v;
    }
    const int b = bh >> 3, hd = bh & 7;
#pragma unroll
    for (int nf = 0; nf < 4; nf++) {
#pragma unroll
        for (int r = 0; r < 4; r++) {
            float val = accO[nf][r] / lsum[r];
            u16 hi, lo; split_bf16(val, hi, lo);
            size_t idx = ((size_t)(b * T_ + qt * 64 + w * 16 + lk * 4 + r)) * D_
                         + hd * 64 + nf * 16 + lr;
            ohi[idx] = hi;
            olo[idx] = lo;
        }
    }
}

// ---------------------------------------------------------------------------
extern "C" void kernel_launch(void* const* d_in, const int* in_sizes, int n_in,
                              void* d_out, int out_size, void* d_ws, size_t ws_size,
                              hipStream_t stream) {
    const int*   x    = (const int*)   d_in[0];
    const float* emb  = (const float*) d_in[1];
    const float* ln1s = (const float*) d_in[2];
    const float* ln1b = (const float*) d_in[3];
    const float* qkvw = (const float*) d_in[4];
    const float* qkvb = (const float*) d_in[5];
    const float* afw  = (const float*) d_in[6];
    const float* afb  = (const float*) d_in[7];
    const float* ln2s = (const float*) d_in[8];
    const float* ln2b = (const float*) d_in[9];
    const float* fw1  = (const float*) d_in[10];
    const float* fb1  = (const float*) d_in[11];
    const float* fw2  = (const float*) d_in[12];
    const float* fb2  = (const float*) d_in[13];
    const float* lnfs = (const float*) d_in[14];
    const float* lnfb = (const float*) d_in[15];
    const float* fcw  = (const float*) d_in[16];
    const float* fcb  = (const float*) d_in[17];
    float* out = (float*)d_out;

    // Workspace (~116 MB), round-6 proven layout:
    // h fp32 | y planes | att planes | qkv 6 planes (Q,K [bh][t][64] hi/lo +
    // V^T [bh][64][t] hi/lo, 25.2 MB) | W planes (single per-layer slot,
    // fc-sized). ff planes alias att+qkv (both dead during FFN).
    float* h     = (float*)d_ws;
    u16*   yhi   = (u16*)(h + (size_t)M_ * D_);
    u16*   ylo   = yhi   + (size_t)M_ * D_;
    u16*   atthi = ylo   + (size_t)M_ * D_;
    u16*   attlo = atthi + (size_t)M_ * D_;
    u16*   qkvp  = attlo + (size_t)M_ * D_;     // 6 * PL_ u16
    u16*   ffhi  = atthi;                        // alias (att+qkv dead in FFN)
    u16*   fflo  = ffhi + (size_t)M_ * FF_;
    u16*   Whi   = qkvp + 6 * (size_t)PL_;
    u16*   Wlo   = Whi + (size_t)D_ * V_;

    // per-layer offsets inside the weight slot (elements)
    const size_t oq = 0, oa = 786432, of1 = 1048576, of2 = 2097152;

    embed_pe_kernel<<<M_, 128, 0, stream>>>(x, emb, h);

    for (int l = 0; l < L_; l++) {
        transpose_split4_kernel<<<3072, 256, 0, stream>>>(
            qkvw + (size_t)l * D_ * 3 * D_, afw + (size_t)l * D_ * D_,
            fw1 + (size_t)l * D_ * FF_, fw2 + (size_t)l * FF_ * D_,
            Whi, Wlo);

        layernorm_kernel<<<M_ / 8, 512, 0, stream>>>(h, ln1s + l * D_, ln1b + l * D_, yhi, ylo);
        // qkv: N=1536, 64^2 tiles, head-separated split output (F_QKV)
        mfma_gemm_t<2, 2><<<dim3(3 * D_ / 64, M_ / 64), 256, 0, stream>>>(
            yhi, ylo, Whi + oq, Wlo + oq, qkvb + l * 3 * D_,
            nullptr, nullptr, nullptr, nullptr, qkvp, 3 * D_, D_, F_QKV);
        // flash: 1-D grid, balanced (qt,bh) pairing (round-6 body)
        flash_mfma_kernel<<<(T_ / 64) * B_ * H_, 256, 0, stream>>>(qkvp, atthi, attlo);
        // attn-fc: N=512, 64^2 tiles -> 512 blocks
        mfma_gemm_t<2, 2><<<dim3(D_ / 64, M_ / 64), 256, 0, stream>>>(
            atthi, attlo, Whi + oa, Wlo + oa, afb + l * D_,
            h, h, nullptr, nullptr, nullptr, D_, D_, F_RES);
        layernorm_kernel<<<M_ / 8, 512, 0, stream>>>(h, ln2s + l * D_, ln2b + l * D_, yhi, ylo);
        // ff1: N=2048, 128^2 tiles -> 512 blocks
        mfma_gemm_t<4, 4><<<dim3(FF_ / 128, M_ / 128), 256, 0, stream>>>(
            yhi, ylo, Whi + of1, Wlo + of1, fb1 + l * FF_,
            nullptr, nullptr, ffhi, fflo, nullptr, FF_, D_, F_GELU | F_SPLIT);
        // ff2: N=512, K=2048 -> 512 blocks
        mfma_gemm_t<2, 2><<<dim3(D_ / 64, M_ / 64), 256, 0, stream>>>(
            ffhi, fflo, Whi + of2, Wlo + of2, fb2 + l * D_,
            h, h, nullptr, nullptr, nullptr, D_, FF_, F_RES);
    }

    transpose_split_kernel<<<dim3(V_ / 32, D_ / 32), dim3(32, 8), 0, stream>>>(
        fcw, Whi, Wlo, D_, V_);
    layernorm_kernel<<<M_ / 8, 512, 0, stream>>>(h, lnfs, lnfb, yhi, ylo);
    // vocab: 128^2 tiles, round-6 F_XCDM mapping (best measured: 410 us)
    mfma_gemm_t<4, 4><<<dim3(V_ / 128, M_ / 128), 256, 0, stream>>>(
        yhi, ylo, Whi, Wlo, fcb, nullptr, out, nullptr, nullptr, nullptr,
        V_, D_, F_XCDM);
}

// Round 12
// 2190.843 us; speedup vs baseline: 1.2106x; 1.1831x over previous
//
#include <hip/hip_runtime.h>
#include <math.h>

typedef unsigned short u16;
typedef unsigned int   u32;

// Problem constants (GPT reference)
#define V_  32000
#define D_  512
#define H_  8
#define DH_ 64
#define L_  8
#define FF_ 2048
#define B_  2
#define T_  2048
#define M_  (B_*T_)   // 4096 token rows

typedef __attribute__((ext_vector_type(8))) _Float16 f16x8;  // 8 fp16 = 4 VGPR
typedef __attribute__((ext_vector_type(4))) float    f32x4;

#define PL_ 2097152    // elements per Q/K/V plane: B*H*T*DH = 16*2048*64
#define WL_ 3145728ull // weight hi-plane elements per layer (qkv+af+ff1+ff2)

// fp16 split: hi = RNE(x), lo = RNE(x - hi).  A-operands use hi+lo (2-pass,
// exact to ~2^-22); B-operands use hi only (weights/K/V: dropped A*B_lo term
// is ~2^-11 relative — error analysis in round-12 notes, ~1e-4 on outputs).
__device__ inline void split_f16(float x, u16& hi, u16& lo) {
    _Float16 h = (_Float16)x;
    _Float16 l = (_Float16)(x - (float)h);
    hi = __builtin_bit_cast(u16, h);
    lo = __builtin_bit_cast(u16, l);
}
__device__ inline u16 f16hi(float x) {
    _Float16 h = (_Float16)x;
    return __builtin_bit_cast(u16, h);
}

// Async global->LDS, 16B per lane. LDS dest = wave-uniform base + lane*16
// (HW behavior, m104/m108); global src is per-lane.
__device__ inline void gload_lds16(const u16* g, u16* l) {
    __builtin_amdgcn_global_load_lds(
        (__attribute__((address_space(1))) void*)(void*)const_cast<u16*>(g),
        (__attribute__((address_space(3))) void*)(void*)l, 16, 0, 0);
}

// ---------------------------------------------------------------------------
// Embedding + positional encoding: h[row,d] = emb[x[row],d] + pe(t,d), fp32
// ---------------------------------------------------------------------------
__global__ void embed_pe_kernel(const int* __restrict__ x,
                                const float* __restrict__ emb,
                                float* __restrict__ h) {
    int row = blockIdx.x;          // 0..M_-1 ; row = b*T + t
    int t   = row % T_;
    int tok = x[row];
    const float* er = emb + (size_t)tok * D_;
    for (int d = threadIdx.x; d < D_; d += blockDim.x) {
        int i = d >> 1;
        float freq = expf((float)(2 * i) * (-9.210340371976184f / (float)D_));
        float ang  = (float)t * freq;
        float pe   = (d & 1) ? cosf(ang) : sinf(ang);
        h[(size_t)row * D_ + d] = er[d] + pe;
    }
}

// ---------------------------------------------------------------------------
// LayerNorm: one wave per row of D=512, 8 waves per block (512 threads).
// fp32 in, split-fp16 planes out (y is an A-operand downstream: hi+lo).
// ---------------------------------------------------------------------------
__global__ __launch_bounds__(512)
void layernorm_kernel(const float* __restrict__ xin,
                      const float* __restrict__ scale,
                      const float* __restrict__ bias,
                      u16* __restrict__ yhi, u16* __restrict__ ylo) {
    int row  = blockIdx.x * 8 + (threadIdx.x >> 6);
    int lane = threadIdx.x & 63;   // 0..63
    const float* xr = xin + (size_t)row * D_;
    float v[8];
    float s = 0.f;
#pragma unroll
    for (int i = 0; i < 8; i++) { v[i] = xr[i * 64 + lane]; s += v[i]; }
#pragma unroll
    for (int off = 32; off; off >>= 1) s += __shfl_xor(s, off, 64);
    float mu = s * (1.0f / D_);
    float var = 0.f;
#pragma unroll
    for (int i = 0; i < 8; i++) { float d0 = v[i] - mu; var += d0 * d0; }
#pragma unroll
    for (int off = 32; off; off >>= 1) var += __shfl_xor(var, off, 64);
    var *= (1.0f / D_);
    float r = rsqrtf(var + 1e-5f);
#pragma unroll
    for (int i = 0; i < 8; i++) {
        int d0 = i * 64 + lane;
        float val = (v[i] - mu) * r * scale[d0] + bias[d0];
        u16 hi, lo; split_f16(val, hi, lo);
        yhi[(size_t)row * D_ + d0] = hi;
        ylo[(size_t)row * D_ + d0] = lo;
    }
}

// ---------------------------------------------------------------------------
// Weight transpose + fp16 hi-split: W[K][N] fp32 -> Thi [N][K] fp16 plane.
// Weights are B-operands only -> hi plane only (half the round-11 traffic).
// Generic single-matrix version (used for fc_w).
// ---------------------------------------------------------------------------
__global__ __launch_bounds__(256)
void transpose_split_kernel(const float* __restrict__ W,
                            u16* __restrict__ Thi, int K, int N) {
    __shared__ float tile[32][33];
    int n0 = blockIdx.x * 32, k0 = blockIdx.y * 32;
    int tx = threadIdx.x, ty = threadIdx.y;   // 32 x 8
#pragma unroll
    for (int i = 0; i < 4; i++) {
        int k = k0 + ty + i * 8;
        tile[ty + i * 8][tx] = W[(size_t)k * N + n0 + tx];   // coalesced in n
    }
    __syncthreads();
#pragma unroll
    for (int i = 0; i < 4; i++) {
        int n = n0 + ty + i * 8;
        Thi[(size_t)n * K + k0 + tx] = f16hi(tile[tx][ty + i * 8]);
    }
}

// ---------------------------------------------------------------------------
// Fused per-layer transpose: all 4 weight matrices in one launch (round-6
// proven placement: per-layer launch keeps the hot slot L2/L3-warm).
// ---------------------------------------------------------------------------
__global__ __launch_bounds__(256)
void transpose_split4_kernel(const float* __restrict__ Wq, const float* __restrict__ Wa,
                             const float* __restrict__ W1, const float* __restrict__ W2,
                             u16* __restrict__ Thi) {
    __shared__ float tile[32][33];
    int id = blockIdx.x;
    const float* W; u16 *thi; int K, N, nt;
    if (id < 768)       { W = Wq; thi = Thi;           K = 512;  N = 1536; nt = 48; }
    else if (id < 1024) { W = Wa; thi = Thi + 786432;  K = 512;  N = 512;  nt = 16; id -= 768; }
    else if (id < 2048) { W = W1; thi = Thi + 1048576; K = 512;  N = 2048; nt = 64; id -= 1024; }
    else                { W = W2; thi = Thi + 2097152; K = 2048; N = 512;  nt = 16; id -= 2048; }
    int n0 = (id % nt) * 32, k0 = (id / nt) * 32;
    int tx = threadIdx.x & 31, ty = threadIdx.x >> 5;   // 32 x 8
#pragma unroll
    for (int i = 0; i < 4; i++) {
        int k = k0 + ty + i * 8;
        tile[ty + i * 8][tx] = W[(size_t)k * N + n0 + tx];
    }
    __syncthreads();
#pragma unroll
    for (int i = 0; i < 4; i++) {
        int n = n0 + ty + i * 8;
        thi[(size_t)n * K + k0 + tx] = f16hi(tile[tx][ty + i * 8]);
    }
}

// ---------------------------------------------------------------------------
// MFMA GEMM, templated tile 32FM x 32FN x 64, 4 waves, fp16 2-pass:
// C = (A_hi + A_lo) x B_hi. Round-6 structure otherwise unchanged:
// single-buffered LDS, {barrier; stage; barrier; compute} per K-step,
// global_load_lds staging, linear LDS dest + inverse-swizzled global source
// col; reads byte ^= (row&7)<<4. LDS: A 2 planes + B 1 plane (<4,4>: 48 KB,
// <2,2>: 24 KB -> occupancy up vs round 11).
// F_XCDM (vocab): xcd = p&7 owns 4 m-tiles, n streams fastest (round-6 best).
// F_QKV epilogue: Q hi+lo [bh][t][64], K hi [bh][t][64], V hi transposed
// [bh][64][t] (feeds MFMA flash directly).
// ---------------------------------------------------------------------------
#define F_GELU  1
#define F_RES   2
#define F_SPLIT 4
#define F_QKV   8
#define F_XCDM  16

template<int FM, int FN>
__global__ __launch_bounds__(256, 2)
void mfma_gemm_t(const u16* __restrict__ Ahi, const u16* __restrict__ Alo,
                 const u16* __restrict__ Bhi,
                 const float* __restrict__ bias, const float* __restrict__ res,
                 float* __restrict__ C, u16* __restrict__ Chi, u16* __restrict__ Clo,
                 u16* __restrict__ qkvp, int N, int K, int flags) {
    constexpr int TBM = 32 * FM, TBN = 32 * FN;
    __shared__ __align__(16) u16 ldsA[2][TBM][64];
    __shared__ __align__(16) u16 ldsB[TBN][64];
    const int tid = threadIdx.x;

    // ---- block -> (m0, n0) ----
    int m0, n0;
    if (flags & F_XCDM) {
        int p    = blockIdx.y * (int)gridDim.x + blockIdx.x;
        int xcd  = p & 7;
        int i    = p >> 3;              // 0..999 within XCD
        int mloc = i / 250;             // 0..3 (n fastest within chunk)
        m0 = (xcd * 4 + mloc) * TBM;
        n0 = (i - mloc * 250) * TBN;
    } else {
        m0 = blockIdx.y * TBM;
        n0 = blockIdx.x * TBN;
    }

    const int wave = tid >> 6;
    const int lane = tid & 63;
    const int wr   = (wave >> 1) * 16 * FM;
    const int wc   = (wave & 1) * 16 * FN;
    const int lr   = lane & 15;
    const int lk   = lane >> 4;

    const int srow = wave * 8 + (lane >> 3);
    const int scol = ((lane & 7) ^ (lane >> 3)) * 8;   // inverse read swizzle
    const u16* As0 = Ahi + (size_t)(m0 + srow) * K + scol;
    const u16* As1 = Alo + (size_t)(m0 + srow) * K + scol;
    const u16* Bs0 = Bhi + (size_t)(n0 + srow) * K + scol;

    f32x4 acc[FM][FN] = {};

    for (int k0 = 0; k0 < K; k0 += 64) {
        __syncthreads();                 // previous tile's compute done
#pragma unroll
        for (int q = 0; q < FM; q++) {
            gload_lds16(As0 + (size_t)q * 32 * K + k0, &ldsA[0][q * 32 + wave * 8][0]);
            gload_lds16(As1 + (size_t)q * 32 * K + k0, &ldsA[1][q * 32 + wave * 8][0]);
        }
#pragma unroll
        for (int q = 0; q < FN; q++) {
            gload_lds16(Bs0 + (size_t)q * 32 * K + k0, &ldsB[q * 32 + wave * 8][0]);
        }
        __syncthreads();                 // drains vmcnt(0) before barrier
#pragma unroll
        for (int ks = 0; ks < 2; ks++) {
            f16x8 ah[FM], al[FM], bhf[FN];
            const int koff = ks * 64 + lk * 16;
#pragma unroll
            for (int f = 0; f < FM; f++) {
                int arow = wr + f * 16 + lr;
                int aoff = koff ^ ((arow & 7) << 4);
                ah[f] = *(const f16x8*)((const char*)(&ldsA[0][arow][0]) + aoff);
                al[f] = *(const f16x8*)((const char*)(&ldsA[1][arow][0]) + aoff);
            }
#pragma unroll
            for (int f = 0; f < FN; f++) {
                int brow = wc + f * 16 + lr;
                int boff = koff ^ ((brow & 7) << 4);
                bhf[f] = *(const f16x8*)((const char*)(&ldsB[brow][0]) + boff);
            }
#pragma unroll
            for (int mf = 0; mf < FM; mf++)
#pragma unroll
                for (int nf = 0; nf < FN; nf++) {
                    acc[mf][nf] = __builtin_amdgcn_mfma_f32_16x16x32_f16(ah[mf], bhf[nf], acc[mf][nf], 0, 0, 0);
                    acc[mf][nf] = __builtin_amdgcn_mfma_f32_16x16x32_f16(al[mf], bhf[nf], acc[mf][nf], 0, 0, 0);
                }
        }
    }

    // ---- epilogue ----
#pragma unroll
    for (int mf = 0; mf < FM; mf++) {
#pragma unroll
        for (int nf = 0; nf < FN; nf++) {
            int col = n0 + wc + nf * 16 + lr;
            float bv = bias[col];
            float cv[4];
            int t0 = m0 + wr + mf * 16 + lk * 4;
#pragma unroll
            for (int r = 0; r < 4; r++) {
                float c = acc[mf][nf][r] + bv;
                if (flags & F_GELU) c = 0.5f * c * (1.0f + erff(c * 0.7071067811865476f));
                if (flags & F_RES)  c += res[(size_t)(t0 + r) * N + col];
                cv[r] = c;
            }
            if (flags & F_QKV) {
                // col -> (section, head, dh); row -> (b, t)
                int sect = col >> 9, hh = (col >> 6) & 7, dh = col & 63;
                int bb = t0 >> 11, tt = t0 & 2047;
                size_t bh = (size_t)bb * 8 + hh;
                if (sect == 2) {         // V hi, transposed: [bh][64][t]
                    ushort4 h4;
                    h4.x = f16hi(cv[0]); h4.y = f16hi(cv[1]);
                    h4.z = f16hi(cv[2]); h4.w = f16hi(cv[3]);
                    size_t vi = (bh * 64 + dh) * T_ + tt;
                    *(ushort4*)(qkvp + 3 * (size_t)PL_ + vi) = h4;
                } else if (sect == 1) {  // K hi only (B-operand of QK^T)
#pragma unroll
                    for (int r = 0; r < 4; r++) {
                        size_t qi = (bh * T_ + tt + r) * 64 + dh;
                        qkvp[2 * (size_t)PL_ + qi] = f16hi(cv[r]);
                    }
                } else {                 // Q hi+lo (A-operand)
#pragma unroll
                    for (int r = 0; r < 4; r++) {
                        u16 hi, lo; split_f16(cv[r], hi, lo);
                        size_t qi = (bh * T_ + tt + r) * 64 + dh;
                        qkvp[qi] = hi;
                        qkvp[PL_ + qi] = lo;
                    }
                }
            } else if (flags & F_SPLIT) {
#pragma unroll
                for (int r = 0; r < 4; r++) {
                    u16 hi, lo; split_f16(cv[r], hi, lo);
                    Chi[(size_t)(t0 + r) * N + col] = hi;
                    Clo[(size_t)(t0 + r) * N + col] = lo;
                }
            } else {
#pragma unroll
                for (int r = 0; r < 4; r++)
                    C[(size_t)(t0 + r) * N + col] = cv[r];
            }
        }
    }
}

// ---------------------------------------------------------------------------
// MFMA causal flash attention (round-6 proven body, fp16 2-pass):
// S = (Q_hi + Q_lo) x K_hi (2 MFMAs/pair), O += P_f16 x V_hi (1 MFMA/pair).
// K_lo / V_lo planes no longer exist -> staging halves; LDS 40 KB
// (Q 2 planes + K + V + P) -> 4 blocks/CU (was 2).
// Block = (qt, bh); 4 waves, wave w owns q rows [w*16, +16) x all 64 keys.
// Balanced mapping: ids u and u+256 get complementary qt (i, 31-i).
// ---------------------------------------------------------------------------
__global__ __launch_bounds__(256)
void flash_mfma_kernel(const u16* __restrict__ qkvp,
                       u16* __restrict__ ohi, u16* __restrict__ olo) {
    const u16* qhp = qkvp;
    const u16* qlp = qkvp + (size_t)PL_;
    const u16* khp = qkvp + 2 * (size_t)PL_;
    const u16* vhp = qkvp + 3 * (size_t)PL_;

    __shared__ __align__(16) u16 Qs[2][64][64];
    __shared__ __align__(16) u16 Ks[64][64];
    __shared__ __align__(16) u16 Vs[64][64];
    __shared__ __align__(16) u16 Ps[64][64];

    // balanced (qt, bh) from flat id: u and u+256 -> (i, 31-i)
    const int u    = blockIdx.x;       // 0..511
    const int r0   = u & 255;
    const int bh   = r0 & 15;          // b*H + head
    const int i0   = r0 >> 4;          // 0..15
    const int qt   = (u >> 8) ? (31 - i0) : i0;

    const int tid = threadIdx.x;
    const int w = tid >> 6, lane = tid & 63;
    const int lr = lane & 15, lk = lane >> 4;

    const int srow = w * 8 + (lane >> 3);
    const int scol = ((lane & 7) ^ (lane >> 3)) * 8;

    // stage Q once (drained by first loop barrier pair)
    {
        size_t qb = ((size_t)bh * T_ + qt * 64 + srow) * 64 + scol;
#pragma unroll
        for (int q = 0; q < 2; q++) {
            gload_lds16(qhp + qb + (size_t)q * 32 * 64, &Qs[0][q * 32 + w * 8][0]);
            gload_lds16(qlp + qb + (size_t)q * 32 * 64, &Qs[1][q * 32 + w * 8][0]);
        }
    }

    f32x4 accO[4] = {};
    float lsum[4] = {0.f, 0.f, 0.f, 0.f};

    for (int kt = 0; kt <= qt; kt++) {
        __syncthreads();               // all waves done reading prev K/V/P
        size_t kb = ((size_t)bh * T_ + kt * 64 + srow) * 64 + scol;
        size_t vb = ((size_t)bh * 64 + srow) * T_ + (size_t)kt * 64 + scol;
#pragma unroll
        for (int q = 0; q < 2; q++) {
            gload_lds16(khp + kb + (size_t)q * 32 * 64, &Ks[q * 32 + w * 8][0]);
            gload_lds16(vhp + vb + (size_t)q * 32 * T_, &Vs[q * 32 + w * 8][0]);
        }
        __syncthreads();               // staging drained (vmcnt 0)

        // ---- S = Q K^T, 2-pass: wave rows [w*16, +16), all 64 keys ----
        f32x4 accS[4] = {};
#pragma unroll
        for (int ks = 0; ks < 2; ks++) {
            const int koff = ks * 64 + lk * 16;
            const int arow = w * 16 + lr;
            const int aoff = koff ^ ((arow & 7) << 4);
            f16x8 qh = *(const f16x8*)((const char*)(&Qs[0][arow][0]) + aoff);
            f16x8 ql = *(const f16x8*)((const char*)(&Qs[1][arow][0]) + aoff);
#pragma unroll
            for (int nf = 0; nf < 4; nf++) {
                int brow = nf * 16 + lr;
                int boff = koff ^ ((brow & 7) << 4);
                f16x8 kh = *(const f16x8*)((const char*)(&Ks[brow][0]) + boff);
                accS[nf] = __builtin_amdgcn_mfma_f32_16x16x32_f16(qh, kh, accS[nf], 0, 0, 0);
                accS[nf] = __builtin_amdgcn_mfma_f32_16x16x32_f16(ql, kh, accS[nf], 0, 0, 0);
            }
        }

        // ---- mask + exp + P->fp16 LDS + row-sum partials ----
        const bool edge = (kt == qt);
#pragma unroll
        for (int nf = 0; nf < 4; nf++) {
            int keyl = nf * 16 + lr;
#pragma unroll
            for (int r = 0; r < 4; r++) {
                int rowl = lk * 4 + r;             // within wave's 16 rows
                float s = accS[nf][r] * 0.125f;
                float p = (!edge || keyl <= w * 16 + rowl) ? __expf(s) : 0.f;
                lsum[r] += p;
                int row = w * 16 + rowl;
                *(u16*)((char*)(&Ps[0][0]) + row * 128 + ((keyl * 2) ^ ((row & 7) << 4))) = f16hi(p);
            }
        }

        // ---- O += P V_hi (1-pass). P rows are same-wave (lgkm orders). ----
#pragma unroll
        for (int kk = 0; kk < 2; kk++) {
            const int koff = kk * 64 + lk * 16;
            const int arow = w * 16 + lr;
            f16x8 pa = *(const f16x8*)((const char*)(&Ps[0][0]) + arow * 128
                                       + (koff ^ ((arow & 7) << 4)));
#pragma unroll
            for (int nf = 0; nf < 4; nf++) {
                int brow = nf * 16 + lr;
                int boff = koff ^ ((brow & 7) << 4);
                f16x8 vh = *(const f16x8*)((const char*)(&Vs[brow][0]) + boff);
                accO[nf] = __builtin_amdgcn_mfma_f32_16x16x32_f16(pa, vh, accO[nf], 0, 0, 0);
            }
        }
    }

    // ---- finish: reduce row sums over the 16-lane col group, write O ----
#pragma unroll
    for (int r = 0; r < 4; r++) {
        float v = lsum[r];
        v += __shfl_xor(v, 1, 64); v += __shfl_xor(v, 2, 64);
        v += __shfl_xor(v, 4, 64); v += __shfl_xor(v, 8, 64);
        lsum[r] = v;
    }
    const int b = bh >> 3, hd = bh & 7;
#pragma unroll
    for (int nf = 0; nf < 4; nf++) {
#pragma unroll
        for (int r = 0; r < 4; r++) {
            float val = accO[nf][r] / lsum[r];
            u16 hi, lo; split_f16(val, hi, lo);
            size_t idx = ((size_t)(b * T_ + qt * 64 + w * 16 + lk * 4 + r)) * D_
                         + hd * 64 + nf * 16 + lr;
            ohi[idx] = hi;
            olo[idx] = lo;
        }
    }
}

// ---------------------------------------------------------------------------
extern "C" void kernel_launch(void* const* d_in, const int* in_sizes, int n_in,
                              void* d_out, int out_size, void* d_ws, size_t ws_size,
                              hipStream_t stream) {
    const int*   x    = (const int*)   d_in[0];
    const float* emb  = (const float*) d_in[1];
    const float* ln1s = (const float*) d_in[2];
    const float* ln1b = (const float*) d_in[3];
    const float* qkvw = (const float*) d_in[4];
    const float* qkvb = (const float*) d_in[5];
    const float* afw  = (const float*) d_in[6];
    const float* afb  = (const float*) d_in[7];
    const float* ln2s = (const float*) d_in[8];
    const float* ln2b = (const float*) d_in[9];
    const float* fw1  = (const float*) d_in[10];
    const float* fb1  = (const float*) d_in[11];
    const float* fw2  = (const float*) d_in[12];
    const float* fb2  = (const float*) d_in[13];
    const float* lnfs = (const float*) d_in[14];
    const float* lnfb = (const float*) d_in[15];
    const float* fcw  = (const float*) d_in[16];
    const float* fcb  = (const float*) d_in[17];
    float* out = (float*)d_out;

    // Workspace (~115 MB):
    //  h        [M,D]  fp32                         8.39 MB
    //  yhi/ylo  [M,D]  fp16 planes                  8.39 MB
    //  atthi/lo [M,D]  fp16 planes                  8.39 MB
    //  qkvp     4 planes (Qhi,Qlo,Khi,VThi)        16.78 MB
    //  ffhi/lo  [M,FF] fp16 planes                 33.55 MB  (own region:
    //           att+qkv alias would be too small at 4 qkv planes)
    //  Whi      per-layer weight hi slot (WL_)      6.29 MB
    //  WhiF     fc weight hi plane                 32.77 MB
    float* h     = (float*)d_ws;
    u16*   yhi   = (u16*)(h + (size_t)M_ * D_);
    u16*   ylo   = yhi   + (size_t)M_ * D_;
    u16*   atthi = ylo   + (size_t)M_ * D_;
    u16*   attlo = atthi + (size_t)M_ * D_;
    u16*   qkvp  = attlo + (size_t)M_ * D_;     // 4 * PL_ u16
    u16*   ffhi  = qkvp  + 4 * (size_t)PL_;
    u16*   fflo  = ffhi  + (size_t)M_ * FF_;
    u16*   Whi   = fflo  + (size_t)M_ * FF_;
    u16*   WhiF  = Whi   + WL_;

    // per-layer offsets inside the weight slot (elements)
    const size_t oq = 0, oa = 786432, of1 = 1048576, of2 = 2097152;

    embed_pe_kernel<<<M_, 128, 0, stream>>>(x, emb, h);

    for (int l = 0; l < L_; l++) {
        transpose_split4_kernel<<<3072, 256, 0, stream>>>(
            qkvw + (size_t)l * D_ * 3 * D_, afw + (size_t)l * D_ * D_,
            fw1 + (size_t)l * D_ * FF_, fw2 + (size_t)l * FF_ * D_, Whi);

        layernorm_kernel<<<M_ / 8, 512, 0, stream>>>(h, ln1s + l * D_, ln1b + l * D_, yhi, ylo);
        // qkv: N=1536, 64^2 tiles, head-separated output (F_QKV)
        mfma_gemm_t<2, 2><<<dim3(3 * D_ / 64, M_ / 64), 256, 0, stream>>>(
            yhi, ylo, Whi + oq, qkvb + l * 3 * D_,
            nullptr, nullptr, nullptr, nullptr, qkvp, 3 * D_, D_, F_QKV);
        // flash: 1-D grid, balanced (qt,bh) pairing (round-6 body, fp16)
        flash_mfma_kernel<<<(T_ / 64) * B_ * H_, 256, 0, stream>>>(qkvp, atthi, attlo);
        // attn-fc: N=512, 64^2 tiles -> 512 blocks
        mfma_gemm_t<2, 2><<<dim3(D_ / 64, M_ / 64), 256, 0, stream>>>(
            atthi, attlo, Whi + oa, afb + l * D_,
            h, h, nullptr, nullptr, nullptr, D_, D_, F_RES);
        layernorm_kernel<<<M_ / 8, 512, 0, stream>>>(h, ln2s + l * D_, ln2b + l * D_, yhi, ylo);
        // ff1: N=2048, 128^2 tiles -> 512 blocks
        mfma_gemm_t<4, 4><<<dim3(FF_ / 128, M_ / 128), 256, 0, stream>>>(
            yhi, ylo, Whi + of1, fb1 + l * FF_,
            nullptr, nullptr, ffhi, fflo, nullptr, FF_, D_, F_GELU | F_SPLIT);
        // ff2: N=512, K=2048 -> 512 blocks
        mfma_gemm_t<2, 2><<<dim3(D_ / 64, M_ / 64), 256, 0, stream>>>(
            ffhi, fflo, Whi + of2, fb2 + l * D_,
            h, h, nullptr, nullptr, nullptr, D_, FF_, F_RES);
    }

    transpose_split_kernel<<<dim3(V_ / 32, D_ / 32), dim3(32, 8), 0, stream>>>(
        fcw, WhiF, D_, V_);
    layernorm_kernel<<<M_ / 8, 512, 0, stream>>>(h, lnfs, lnfb, yhi, ylo);
    // vocab: 128^2 tiles, round-6 F_XCDM mapping
    mfma_gemm_t<4, 4><<<dim3(V_ / 128, M_ / 128), 256, 0, stream>>>(
        yhi, ylo, WhiF, fcb, nullptr, out, nullptr, nullptr, nullptr,
        V_, D_, F_XCDM);
}

// Round 13
// 2135.255 us; speedup vs baseline: 1.2421x; 1.0260x over previous
//
#include <hip/hip_runtime.h>
#include <math.h>

typedef unsigned short u16;
typedef unsigned int   u32;

// Problem constants (GPT reference)
#define V_  32000
#define D_  512
#define H_  8
#define DH_ 64
#define L_  8
#define FF_ 2048
#define B_  2
#define T_  2048
#define M_  (B_*T_)   // 4096 token rows

typedef __attribute__((ext_vector_type(8))) _Float16 f16x8;  // 8 fp16 = 4 VGPR
typedef __attribute__((ext_vector_type(4))) float    f32x4;

#define PL_ 2097152    // elements per Q/K/V plane: B*H*T*DH = 16*2048*64
#define WL_ 3145728ull // weight hi-plane elements per layer (qkv+af+ff1+ff2)

// fp16 split: hi = RNE(x), lo = RNE(x - hi).  A-operands use hi+lo (2-pass,
// exact to ~2^-22); B-operands use hi only. Vocab GEMM additionally drops
// A_lo (final LN output, no downstream compounding): +4.5e-4 logits error,
// 30x under the 0.0156 absmax floor (unchanged rounds 1-12).
__device__ inline void split_f16(float x, u16& hi, u16& lo) {
    _Float16 h = (_Float16)x;
    _Float16 l = (_Float16)(x - (float)h);
    hi = __builtin_bit_cast(u16, h);
    lo = __builtin_bit_cast(u16, l);
}
__device__ inline u16 f16hi(float x) {
    _Float16 h = (_Float16)x;
    return __builtin_bit_cast(u16, h);
}

// Async global->LDS, 16B per lane. LDS dest = wave-uniform base + lane*16
// (HW behavior, m104/m108); global src is per-lane.
__device__ inline void gload_lds16(const u16* g, u16* l) {
    __builtin_amdgcn_global_load_lds(
        (__attribute__((address_space(1))) void*)(void*)const_cast<u16*>(g),
        (__attribute__((address_space(3))) void*)(void*)l, 16, 0, 0);
}

// ---------------------------------------------------------------------------
// Embedding + positional encoding: h[row,d] = emb[x[row],d] + pe(t,d), fp32
// ---------------------------------------------------------------------------
__global__ void embed_pe_kernel(const int* __restrict__ x,
                                const float* __restrict__ emb,
                                float* __restrict__ h) {
    int row = blockIdx.x;          // 0..M_-1 ; row = b*T + t
    int t   = row % T_;
    int tok = x[row];
    const float* er = emb + (size_t)tok * D_;
    for (int d = threadIdx.x; d < D_; d += blockDim.x) {
        int i = d >> 1;
        float freq = expf((float)(2 * i) * (-9.210340371976184f / (float)D_));
        float ang  = (float)t * freq;
        float pe   = (d & 1) ? cosf(ang) : sinf(ang);
        h[(size_t)row * D_ + d] = er[d] + pe;
    }
}

// ---------------------------------------------------------------------------
// LayerNorm: one wave per row of D=512, 8 waves per block (512 threads).
// fp32 in, split-fp16 planes out (y is an A-operand downstream: hi+lo).
// ---------------------------------------------------------------------------
__global__ __launch_bounds__(512)
void layernorm_kernel(const float* __restrict__ xin,
                      const float* __restrict__ scale,
                      const float* __restrict__ bias,
                      u16* __restrict__ yhi, u16* __restrict__ ylo) {
    int row  = blockIdx.x * 8 + (threadIdx.x >> 6);
    int lane = threadIdx.x & 63;   // 0..63
    const float* xr = xin + (size_t)row * D_;
    float v[8];
    float s = 0.f;
#pragma unroll
    for (int i = 0; i < 8; i++) { v[i] = xr[i * 64 + lane]; s += v[i]; }
#pragma unroll
    for (int off = 32; off; off >>= 1) s += __shfl_xor(s, off, 64);
    float mu = s * (1.0f / D_);
    float var = 0.f;
#pragma unroll
    for (int i = 0; i < 8; i++) { float d0 = v[i] - mu; var += d0 * d0; }
#pragma unroll
    for (int off = 32; off; off >>= 1) var += __shfl_xor(var, off, 64);
    var *= (1.0f / D_);
    float r = rsqrtf(var + 1e-5f);
#pragma unroll
    for (int i = 0; i < 8; i++) {
        int d0 = i * 64 + lane;
        float val = (v[i] - mu) * r * scale[d0] + bias[d0];
        u16 hi, lo; split_f16(val, hi, lo);
        yhi[(size_t)row * D_ + d0] = hi;
        ylo[(size_t)row * D_ + d0] = lo;
    }
}

// ---------------------------------------------------------------------------
// Weight transpose + fp16 hi-split: W[K][N] fp32 -> Thi [N][K] fp16 plane.
// Generic single-matrix version (used for fc_w).
// ---------------------------------------------------------------------------
__global__ __launch_bounds__(256)
void transpose_split_kernel(const float* __restrict__ W,
                            u16* __restrict__ Thi, int K, int N) {
    __shared__ float tile[32][33];
    int n0 = blockIdx.x * 32, k0 = blockIdx.y * 32;
    int tx = threadIdx.x, ty = threadIdx.y;   // 32 x 8
#pragma unroll
    for (int i = 0; i < 4; i++) {
        int k = k0 + ty + i * 8;
        tile[ty + i * 8][tx] = W[(size_t)k * N + n0 + tx];   // coalesced in n
    }
    __syncthreads();
#pragma unroll
    for (int i = 0; i < 4; i++) {
        int n = n0 + ty + i * 8;
        Thi[(size_t)n * K + k0 + tx] = f16hi(tile[tx][ty + i * 8]);
    }
}

// ---------------------------------------------------------------------------
// Fused per-layer transpose: all 4 weight matrices in one launch (round-6
// proven placement: per-layer launch keeps the hot slot L2/L3-warm).
// ---------------------------------------------------------------------------
__global__ __launch_bounds__(256)
void transpose_split4_kernel(const float* __restrict__ Wq, const float* __restrict__ Wa,
                             const float* __restrict__ W1, const float* __restrict__ W2,
                             u16* __restrict__ Thi) {
    __shared__ float tile[32][33];
    int id = blockIdx.x;
    const float* W; u16 *thi; int K, N, nt;
    if (id < 768)       { W = Wq; thi = Thi;           K = 512;  N = 1536; nt = 48; }
    else if (id < 1024) { W = Wa; thi = Thi + 786432;  K = 512;  N = 512;  nt = 16; id -= 768; }
    else if (id < 2048) { W = W1; thi = Thi + 1048576; K = 512;  N = 2048; nt = 64; id -= 1024; }
    else                { W = W2; thi = Thi + 2097152; K = 2048; N = 512;  nt = 16; id -= 2048; }
    int n0 = (id % nt) * 32, k0 = (id / nt) * 32;
    int tx = threadIdx.x & 31, ty = threadIdx.x >> 5;   // 32 x 8
#pragma unroll
    for (int i = 0; i < 4; i++) {
        int k = k0 + ty + i * 8;
        tile[ty + i * 8][tx] = W[(size_t)k * N + n0 + tx];
    }
    __syncthreads();
#pragma unroll
    for (int i = 0; i < 4; i++) {
        int n = n0 + ty + i * 8;
        thi[(size_t)n * K + k0 + tx] = f16hi(tile[tx][ty + i * 8]);
    }
}

// ---------------------------------------------------------------------------
// MFMA GEMM, templated tile 32FM x 32FN x 64, 4 waves.
// TP=true : C = (A_hi + A_lo) x B_hi  (2-pass, activations in the residual
//           path — error must not compound).
// TP=false: C = A_hi x B_hi           (1-pass, vocab only: final LN output,
//           LDS A-planes halve (32 KB at <4,4>), MFMA count halves).
// Round-6 structure otherwise: single-buffered LDS, {barrier; stage;
// barrier; compute} per K-step, global_load_lds staging, linear LDS dest +
// inverse-swizzled global source col; reads byte ^= (row&7)<<4.
// F_XCDM (vocab): xcd = p&7 owns 4 m-tiles, n streams fastest (round-6 best).
// F_QKV epilogue: Q hi+lo [bh][t][64], K hi [bh][t][64], V hi transposed
// [bh][64][t] (feeds MFMA flash directly).
// ---------------------------------------------------------------------------
#define F_GELU  1
#define F_RES   2
#define F_SPLIT 4
#define F_QKV   8
#define F_XCDM  16

template<int FM, int FN, bool TP>
__global__ __launch_bounds__(256, 2)
void mfma_gemm_t(const u16* __restrict__ Ahi, const u16* __restrict__ Alo,
                 const u16* __restrict__ Bhi,
                 const float* __restrict__ bias, const float* __restrict__ res,
                 float* __restrict__ C, u16* __restrict__ Chi, u16* __restrict__ Clo,
                 u16* __restrict__ qkvp, int N, int K, int flags) {
    constexpr int TBM = 32 * FM, TBN = 32 * FN;
    constexpr int AP  = TP ? 2 : 1;
    __shared__ __align__(16) u16 ldsA[AP][TBM][64];
    __shared__ __align__(16) u16 ldsB[TBN][64];
    const int tid = threadIdx.x;

    // ---- block -> (m0, n0) ----
    int m0, n0;
    if (flags & F_XCDM) {
        int p    = blockIdx.y * (int)gridDim.x + blockIdx.x;
        int xcd  = p & 7;
        int i    = p >> 3;              // 0..999 within XCD
        int mloc = i / 250;             // 0..3 (n fastest within chunk)
        m0 = (xcd * 4 + mloc) * TBM;
        n0 = (i - mloc * 250) * TBN;
    } else {
        m0 = blockIdx.y * TBM;
        n0 = blockIdx.x * TBN;
    }

    const int wave = tid >> 6;
    const int lane = tid & 63;
    const int wr   = (wave >> 1) * 16 * FM;
    const int wc   = (wave & 1) * 16 * FN;
    const int lr   = lane & 15;
    const int lk   = lane >> 4;

    const int srow = wave * 8 + (lane >> 3);
    const int scol = ((lane & 7) ^ (lane >> 3)) * 8;   // inverse read swizzle
    const u16* As0 = Ahi + (size_t)(m0 + srow) * K + scol;
    const u16* As1 = nullptr;
    if constexpr (TP) As1 = Alo + (size_t)(m0 + srow) * K + scol;
    const u16* Bs0 = Bhi + (size_t)(n0 + srow) * K + scol;

    f32x4 acc[FM][FN] = {};

    for (int k0 = 0; k0 < K; k0 += 64) {
        __syncthreads();                 // previous tile's compute done
#pragma unroll
        for (int q = 0; q < FM; q++) {
            gload_lds16(As0 + (size_t)q * 32 * K + k0, &ldsA[0][q * 32 + wave * 8][0]);
            if constexpr (TP)
                gload_lds16(As1 + (size_t)q * 32 * K + k0, &ldsA[AP - 1][q * 32 + wave * 8][0]);
        }
#pragma unroll
        for (int q = 0; q < FN; q++) {
            gload_lds16(Bs0 + (size_t)q * 32 * K + k0, &ldsB[q * 32 + wave * 8][0]);
        }
        __syncthreads();                 // drains vmcnt(0) before barrier
#pragma unroll
        for (int ks = 0; ks < 2; ks++) {
            f16x8 ah[FM], al[FM], bhf[FN];
            const int koff = ks * 64 + lk * 16;
#pragma unroll
            for (int f = 0; f < FM; f++) {
                int arow = wr + f * 16 + lr;
                int aoff = koff ^ ((arow & 7) << 4);
                ah[f] = *(const f16x8*)((const char*)(&ldsA[0][arow][0]) + aoff);
                if constexpr (TP)
                    al[f] = *(const f16x8*)((const char*)(&ldsA[AP - 1][arow][0]) + aoff);
            }
#pragma unroll
            for (int f = 0; f < FN; f++) {
                int brow = wc + f * 16 + lr;
                int boff = koff ^ ((brow & 7) << 4);
                bhf[f] = *(const f16x8*)((const char*)(&ldsB[brow][0]) + boff);
            }
#pragma unroll
            for (int mf = 0; mf < FM; mf++)
#pragma unroll
                for (int nf = 0; nf < FN; nf++) {
                    acc[mf][nf] = __builtin_amdgcn_mfma_f32_16x16x32_f16(ah[mf], bhf[nf], acc[mf][nf], 0, 0, 0);
                    if constexpr (TP)
                        acc[mf][nf] = __builtin_amdgcn_mfma_f32_16x16x32_f16(al[mf], bhf[nf], acc[mf][nf], 0, 0, 0);
                }
        }
    }

    // ---- epilogue ----
#pragma unroll
    for (int mf = 0; mf < FM; mf++) {
#pragma unroll
        for (int nf = 0; nf < FN; nf++) {
            int col = n0 + wc + nf * 16 + lr;
            float bv = bias[col];
            float cv[4];
            int t0 = m0 + wr + mf * 16 + lk * 4;
#pragma unroll
            for (int r = 0; r < 4; r++) {
                float c = acc[mf][nf][r] + bv;
                if (flags & F_GELU) c = 0.5f * c * (1.0f + erff(c * 0.7071067811865476f));
                if (flags & F_RES)  c += res[(size_t)(t0 + r) * N + col];
                cv[r] = c;
            }
            if (flags & F_QKV) {
                // col -> (section, head, dh); row -> (b, t)
                int sect = col >> 9, hh = (col >> 6) & 7, dh = col & 63;
                int bb = t0 >> 11, tt = t0 & 2047;
                size_t bh = (size_t)bb * 8 + hh;
                if (sect == 2) {         // V hi, transposed: [bh][64][t]
                    ushort4 h4;
                    h4.x = f16hi(cv[0]); h4.y = f16hi(cv[1]);
                    h4.z = f16hi(cv[2]); h4.w = f16hi(cv[3]);
                    size_t vi = (bh * 64 + dh) * T_ + tt;
                    *(ushort4*)(qkvp + 3 * (size_t)PL_ + vi) = h4;
                } else if (sect == 1) {  // K hi only (B-operand of QK^T)
#pragma unroll
                    for (int r = 0; r < 4; r++) {
                        size_t qi = (bh * T_ + tt + r) * 64 + dh;
                        qkvp[2 * (size_t)PL_ + qi] = f16hi(cv[r]);
                    }
                } else {                 // Q hi+lo (A-operand)
#pragma unroll
                    for (int r = 0; r < 4; r++) {
                        u16 hi, lo; split_f16(cv[r], hi, lo);
                        size_t qi = (bh * T_ + tt + r) * 64 + dh;
                        qkvp[qi] = hi;
                        qkvp[PL_ + qi] = lo;
                    }
                }
            } else if (flags & F_SPLIT) {
#pragma unroll
                for (int r = 0; r < 4; r++) {
                    u16 hi, lo; split_f16(cv[r], hi, lo);
                    Chi[(size_t)(t0 + r) * N + col] = hi;
                    Clo[(size_t)(t0 + r) * N + col] = lo;
                }
            } else {
#pragma unroll
                for (int r = 0; r < 4; r++)
                    C[(size_t)(t0 + r) * N + col] = cv[r];
            }
        }
    }
}

// ---------------------------------------------------------------------------
// MFMA causal flash attention, fp16, PAIRED K/V staging (round-13):
// stage TWO 64-key tiles per barrier pair (LDS 56 KB: Q 2 planes + K[2] +
// V[2] + P), then run the (unchanged, bit-identical) 64-key compute body
// once per staged sub-tile. Barrier pairs per block halve (<=16 vs <=32)
// and each vmcnt drain is amortized over 2x the MFMA work.
// S = (Q_hi + Q_lo) x K_hi (2-pass), O += P_f16 x V_hi (1-pass).
// Block = (qt, bh); 4 waves, wave w owns q rows [w*16, +16) x all 64 keys.
// Balanced mapping: ids u and u+256 get complementary qt (i, 31-i).
// ---------------------------------------------------------------------------
__global__ __launch_bounds__(256)
void flash_mfma_kernel(const u16* __restrict__ qkvp,
                       u16* __restrict__ ohi, u16* __restrict__ olo) {
    const u16* qhp = qkvp;
    const u16* qlp = qkvp + (size_t)PL_;
    const u16* khp = qkvp + 2 * (size_t)PL_;
    const u16* vhp = qkvp + 3 * (size_t)PL_;

    __shared__ __align__(16) u16 Qs[2][64][64];
    __shared__ __align__(16) u16 Ks[2][64][64];   // [subtile][key][dh]
    __shared__ __align__(16) u16 Vs[2][64][64];   // [subtile][dh][key]
    __shared__ __align__(16) u16 Ps[64][64];

    // balanced (qt, bh) from flat id: u and u+256 -> (i, 31-i)
    const int u    = blockIdx.x;       // 0..511
    const int r0   = u & 255;
    const int bh   = r0 & 15;          // b*H + head
    const int i0   = r0 >> 4;          // 0..15
    const int qt   = (u >> 8) ? (31 - i0) : i0;

    const int tid = threadIdx.x;
    const int w = tid >> 6, lane = tid & 63;
    const int lr = lane & 15, lk = lane >> 4;

    const int srow = w * 8 + (lane >> 3);
    const int scol = ((lane & 7) ^ (lane >> 3)) * 8;

    // stage Q once (drained by first loop barrier pair)
    {
        size_t qb = ((size_t)bh * T_ + qt * 64 + srow) * 64 + scol;
#pragma unroll
        for (int q = 0; q < 2; q++) {
            gload_lds16(qhp + qb + (size_t)q * 32 * 64, &Qs[0][q * 32 + w * 8][0]);
            gload_lds16(qlp + qb + (size_t)q * 32 * 64, &Qs[1][q * 32 + w * 8][0]);
        }
    }

    f32x4 accO[4] = {};
    float lsum[4] = {0.f, 0.f, 0.f, 0.f};

    auto stageKV = [&](int kt, int s) {
        size_t kb = ((size_t)bh * T_ + kt * 64 + srow) * 64 + scol;
        size_t vb = ((size_t)bh * 64 + srow) * T_ + (size_t)kt * 64 + scol;
#pragma unroll
        for (int q = 0; q < 2; q++) {
            gload_lds16(khp + kb + (size_t)q * 32 * 64, &Ks[s][q * 32 + w * 8][0]);
            gload_lds16(vhp + vb + (size_t)q * 32 * T_, &Vs[s][q * 32 + w * 8][0]);
        }
    };

    auto compute = [&](int kt, int s) {
        // ---- S = Q K^T, 2-pass: wave rows [w*16, +16), all 64 keys ----
        f32x4 accS[4] = {};
#pragma unroll
        for (int ks = 0; ks < 2; ks++) {
            const int koff = ks * 64 + lk * 16;
            const int arow = w * 16 + lr;
            const int aoff = koff ^ ((arow & 7) << 4);
            f16x8 qh = *(const f16x8*)((const char*)(&Qs[0][arow][0]) + aoff);
            f16x8 ql = *(const f16x8*)((const char*)(&Qs[1][arow][0]) + aoff);
#pragma unroll
            for (int nf = 0; nf < 4; nf++) {
                int brow = nf * 16 + lr;
                int boff = koff ^ ((brow & 7) << 4);
                f16x8 kh = *(const f16x8*)((const char*)(&Ks[s][brow][0]) + boff);
                accS[nf] = __builtin_amdgcn_mfma_f32_16x16x32_f16(qh, kh, accS[nf], 0, 0, 0);
                accS[nf] = __builtin_amdgcn_mfma_f32_16x16x32_f16(ql, kh, accS[nf], 0, 0, 0);
            }
        }

        // ---- mask + exp + P->fp16 LDS + row-sum partials ----
        const bool edge = (kt == qt);
#pragma unroll
        for (int nf = 0; nf < 4; nf++) {
            int keyl = nf * 16 + lr;
#pragma unroll
            for (int r = 0; r < 4; r++) {
                int rowl = lk * 4 + r;             // within wave's 16 rows
                float sv = accS[nf][r] * 0.125f;
                float p = (!edge || keyl <= w * 16 + rowl) ? __expf(sv) : 0.f;
                lsum[r] += p;
                int row = w * 16 + rowl;
                *(u16*)((char*)(&Ps[0][0]) + row * 128 + ((keyl * 2) ^ ((row & 7) << 4))) = f16hi(p);
            }
        }

        // ---- O += P V_hi (1-pass). P rows are same-wave (lgkm orders). ----
#pragma unroll
        for (int kk = 0; kk < 2; kk++) {
            const int koff = kk * 64 + lk * 16;
            const int arow = w * 16 + lr;
            f16x8 pa = *(const f16x8*)((const char*)(&Ps[0][0]) + arow * 128
                                       + (koff ^ ((arow & 7) << 4)));
#pragma unroll
            for (int nf = 0; nf < 4; nf++) {
                int brow = nf * 16 + lr;
                int boff = koff ^ ((brow & 7) << 4);
                f16x8 vh = *(const f16x8*)((const char*)(&Vs[s][brow][0]) + boff);
                accO[nf] = __builtin_amdgcn_mfma_f32_16x16x32_f16(pa, vh, accO[nf], 0, 0, 0);
            }
        }
    };

    for (int ktp = 0; ktp <= qt; ktp += 2) {
        const bool two = (ktp + 1 <= qt);
        __syncthreads();               // all waves done reading prev K/V
        stageKV(ktp, 0);
        if (two) stageKV(ktp + 1, 1);
        __syncthreads();               // staging drained (vmcnt 0)
        compute(ktp, 0);
        if (two) compute(ktp + 1, 1);
    }

    // ---- finish: reduce row sums over the 16-lane col group, write O ----
#pragma unroll
    for (int r = 0; r < 4; r++) {
        float v = lsum[r];
        v += __shfl_xor(v, 1, 64); v += __shfl_xor(v, 2, 64);
        v += __shfl_xor(v, 4, 64); v += __shfl_xor(v, 8, 64);
        lsum[r] = v;
    }
    const int b = bh >> 3, hd = bh & 7;
#pragma unroll
    for (int nf = 0; nf < 4; nf++) {
#pragma unroll
        for (int r = 0; r < 4; r++) {
            float val = accO[nf][r] / lsum[r];
            u16 hi, lo; split_f16(val, hi, lo);
            size_t idx = ((size_t)(b * T_ + qt * 64 + w * 16 + lk * 4 + r)) * D_
                         + hd * 64 + nf * 16 + lr;
            ohi[idx] = hi;
            olo[idx] = lo;
        }
    }
}

// ---------------------------------------------------------------------------
extern "C" void kernel_launch(void* const* d_in, const int* in_sizes, int n_in,
                              void* d_out, int out_size, void* d_ws, size_t ws_size,
                              hipStream_t stream) {
    const int*   x    = (const int*)   d_in[0];
    const float* emb  = (const float*) d_in[1];
    const float* ln1s = (const float*) d_in[2];
    const float* ln1b = (const float*) d_in[3];
    const float* qkvw = (const float*) d_in[4];
    const float* qkvb = (const float*) d_in[5];
    const float* afw  = (const float*) d_in[6];
    const float* afb  = (const float*) d_in[7];
    const float* ln2s = (const float*) d_in[8];
    const float* ln2b = (const float*) d_in[9];
    const float* fw1  = (const float*) d_in[10];
    const float* fb1  = (const float*) d_in[11];
    const float* fw2  = (const float*) d_in[12];
    const float* fb2  = (const float*) d_in[13];
    const float* lnfs = (const float*) d_in[14];
    const float* lnfb = (const float*) d_in[15];
    const float* fcw  = (const float*) d_in[16];
    const float* fcb  = (const float*) d_in[17];
    float* out = (float*)d_out;

    // Workspace (~115 MB), round-12 layout:
    //  h fp32 | yhi/ylo | atthi/attlo | qkvp 4 planes (Qhi,Qlo,Khi,VThi) |
    //  ffhi/fflo | Whi per-layer slot | WhiF fc plane.
    float* h     = (float*)d_ws;
    u16*   yhi   = (u16*)(h + (size_t)M_ * D_);
    u16*   ylo   = yhi   + (size_t)M_ * D_;
    u16*   atthi = ylo   + (size_t)M_ * D_;
    u16*   attlo = atthi + (size_t)M_ * D_;
    u16*   qkvp  = attlo + (size_t)M_ * D_;     // 4 * PL_ u16
    u16*   ffhi  = qkvp  + 4 * (size_t)PL_;
    u16*   fflo  = ffhi  + (size_t)M_ * FF_;
    u16*   Whi   = fflo  + (size_t)M_ * FF_;
    u16*   WhiF  = Whi   + WL_;

    // per-layer offsets inside the weight slot (elements)
    const size_t oq = 0, oa = 786432, of1 = 1048576, of2 = 2097152;

    embed_pe_kernel<<<M_, 128, 0, stream>>>(x, emb, h);

    for (int l = 0; l < L_; l++) {
        transpose_split4_kernel<<<3072, 256, 0, stream>>>(
            qkvw + (size_t)l * D_ * 3 * D_, afw + (size_t)l * D_ * D_,
            fw1 + (size_t)l * D_ * FF_, fw2 + (size_t)l * FF_ * D_, Whi);

        layernorm_kernel<<<M_ / 8, 512, 0, stream>>>(h, ln1s + l * D_, ln1b + l * D_, yhi, ylo);
        // qkv: N=1536, 64^2 tiles, head-separated output (F_QKV)
        mfma_gemm_t<2, 2, true><<<dim3(3 * D_ / 64, M_ / 64), 256, 0, stream>>>(
            yhi, ylo, Whi + oq, qkvb + l * 3 * D_,
            nullptr, nullptr, nullptr, nullptr, qkvp, 3 * D_, D_, F_QKV);
        // flash: 1-D grid, balanced (qt,bh) pairing, paired K/V staging
        flash_mfma_kernel<<<(T_ / 64) * B_ * H_, 256, 0, stream>>>(qkvp, atthi, attlo);
        // attn-fc: N=512, 64^2 tiles -> 512 blocks
        mfma_gemm_t<2, 2, true><<<dim3(D_ / 64, M_ / 64), 256, 0, stream>>>(
            atthi, attlo, Whi + oa, afb + l * D_,
            h, h, nullptr, nullptr, nullptr, D_, D_, F_RES);
        layernorm_kernel<<<M_ / 8, 512, 0, stream>>>(h, ln2s + l * D_, ln2b + l * D_, yhi, ylo);
        // ff1: N=2048, 128^2 tiles -> 512 blocks
        mfma_gemm_t<4, 4, true><<<dim3(FF_ / 128, M_ / 128), 256, 0, stream>>>(
            yhi, ylo, Whi + of1, fb1 + l * FF_,
            nullptr, nullptr, ffhi, fflo, nullptr, FF_, D_, F_GELU | F_SPLIT);
        // ff2: N=512, K=2048 -> 512 blocks
        mfma_gemm_t<2, 2, true><<<dim3(D_ / 64, M_ / 64), 256, 0, stream>>>(
            ffhi, fflo, Whi + of2, fb2 + l * D_,
            h, h, nullptr, nullptr, nullptr, D_, FF_, F_RES);
    }

    transpose_split_kernel<<<dim3(V_ / 32, D_ / 32), dim3(32, 8), 0, stream>>>(
        fcw, WhiF, D_, V_);
    layernorm_kernel<<<M_ / 8, 512, 0, stream>>>(h, lnfs, lnfb, yhi, ylo);
    // vocab: 128^2 tiles, F_XCDM mapping, SINGLE-PASS A (TP=false)
    mfma_gemm_t<4, 4, false><<<dim3(V_ / 128, M_ / 128), 256, 0, stream>>>(
        yhi, nullptr, WhiF, fcb, nullptr, out, nullptr, nullptr, nullptr,
        V_, D_, F_XCDM);
}

// Round 14
// 2014.210 us; speedup vs baseline: 1.3168x; 1.0601x over previous
//
#include <hip/hip_runtime.h>
#include <math.h>

typedef unsigned short u16;
typedef unsigned int   u32;

// Problem constants (GPT reference)
#define V_  32000
#define D_  512
#define H_  8
#define DH_ 64
#define L_  8
#define FF_ 2048
#define B_  2
#define T_  2048
#define M_  (B_*T_)   // 4096 token rows

typedef __attribute__((ext_vector_type(8))) _Float16 f16x8;  // 8 fp16 = 4 VGPR
typedef __attribute__((ext_vector_type(4))) float    f32x4;

#define PL_ 2097152    // elements per Q/K/V plane: B*H*T*DH = 16*2048*64
#define WL_ 3145728ull // weight hi-plane elements per layer (qkv+af+ff1+ff2)

// fp16 split: hi = RNE(x), lo = RNE(x - hi).
// Numerics (empirically validated, rounds 12-13: absmax invariant at
// 0.015625 across B-side 2^-11 rounding on EVERY GEMM and vocab A_lo drop):
//  - residual-writing GEMMs (attn-fc, ff2) keep 2-pass A (hi+lo): the
//    residual stream is the only linear-compounding path.
//  - all other A operands (y -> qkv/ff1/vocab, Q in flash) are hi-only.
__device__ inline void split_f16(float x, u16& hi, u16& lo) {
    _Float16 h = (_Float16)x;
    _Float16 l = (_Float16)(x - (float)h);
    hi = __builtin_bit_cast(u16, h);
    lo = __builtin_bit_cast(u16, l);
}
__device__ inline u16 f16hi(float x) {
    _Float16 h = (_Float16)x;
    return __builtin_bit_cast(u16, h);
}

// Async global->LDS, 16B per lane. LDS dest = wave-uniform base + lane*16
// (HW behavior, m104/m108); global src is per-lane.
__device__ inline void gload_lds16(const u16* g, u16* l) {
    __builtin_amdgcn_global_load_lds(
        (__attribute__((address_space(1))) void*)(void*)const_cast<u16*>(g),
        (__attribute__((address_space(3))) void*)(void*)l, 16, 0, 0);
}

// ---------------------------------------------------------------------------
// Embedding + positional encoding: h[row,d] = emb[x[row],d] + pe(t,d), fp32
// ---------------------------------------------------------------------------
__global__ void embed_pe_kernel(const int* __restrict__ x,
                                const float* __restrict__ emb,
                                float* __restrict__ h) {
    int row = blockIdx.x;          // 0..M_-1 ; row = b*T + t
    int t   = row % T_;
    int tok = x[row];
    const float* er = emb + (size_t)tok * D_;
    for (int d = threadIdx.x; d < D_; d += blockDim.x) {
        int i = d >> 1;
        float freq = expf((float)(2 * i) * (-9.210340371976184f / (float)D_));
        float ang  = (float)t * freq;
        float pe   = (d & 1) ? cosf(ang) : sinf(ang);
        h[(size_t)row * D_ + d] = er[d] + pe;
    }
}

// ---------------------------------------------------------------------------
// LayerNorm: one wave per row of D=512, 8 waves per block (512 threads).
// fp32 in, fp16 HI plane out only (y feeds hi-only GEMMs: qkv/ff1/vocab).
// ---------------------------------------------------------------------------
__global__ __launch_bounds__(512)
void layernorm_kernel(const float* __restrict__ xin,
                      const float* __restrict__ scale,
                      const float* __restrict__ bias,
                      u16* __restrict__ yhi) {
    int row  = blockIdx.x * 8 + (threadIdx.x >> 6);
    int lane = threadIdx.x & 63;   // 0..63
    const float* xr = xin + (size_t)row * D_;
    float v[8];
    float s = 0.f;
#pragma unroll
    for (int i = 0; i < 8; i++) { v[i] = xr[i * 64 + lane]; s += v[i]; }
#pragma unroll
    for (int off = 32; off; off >>= 1) s += __shfl_xor(s, off, 64);
    float mu = s * (1.0f / D_);
    float var = 0.f;
#pragma unroll
    for (int i = 0; i < 8; i++) { float d0 = v[i] - mu; var += d0 * d0; }
#pragma unroll
    for (int off = 32; off; off >>= 1) var += __shfl_xor(var, off, 64);
    var *= (1.0f / D_);
    float r = rsqrtf(var + 1e-5f);
#pragma unroll
    for (int i = 0; i < 8; i++) {
        int d0 = i * 64 + lane;
        float val = (v[i] - mu) * r * scale[d0] + bias[d0];
        yhi[(size_t)row * D_ + d0] = f16hi(val);
    }
}

// ---------------------------------------------------------------------------
// Weight transpose + fp16 hi-split: W[K][N] fp32 -> Thi [N][K] fp16 plane.
// Generic single-matrix version (used for fc_w).
// ---------------------------------------------------------------------------
__global__ __launch_bounds__(256)
void transpose_split_kernel(const float* __restrict__ W,
                            u16* __restrict__ Thi, int K, int N) {
    __shared__ float tile[32][33];
    int n0 = blockIdx.x * 32, k0 = blockIdx.y * 32;
    int tx = threadIdx.x, ty = threadIdx.y;   // 32 x 8
#pragma unroll
    for (int i = 0; i < 4; i++) {
        int k = k0 + ty + i * 8;
        tile[ty + i * 8][tx] = W[(size_t)k * N + n0 + tx];   // coalesced in n
    }
    __syncthreads();
#pragma unroll
    for (int i = 0; i < 4; i++) {
        int n = n0 + ty + i * 8;
        Thi[(size_t)n * K + k0 + tx] = f16hi(tile[tx][ty + i * 8]);
    }
}

// ---------------------------------------------------------------------------
// Fused per-layer transpose: all 4 weight matrices in one launch (round-6
// proven placement: per-layer launch keeps the hot slot L2/L3-warm).
// ---------------------------------------------------------------------------
__global__ __launch_bounds__(256)
void transpose_split4_kernel(const float* __restrict__ Wq, const float* __restrict__ Wa,
                             const float* __restrict__ W1, const float* __restrict__ W2,
                             u16* __restrict__ Thi) {
    __shared__ float tile[32][33];
    int id = blockIdx.x;
    const float* W; u16 *thi; int K, N, nt;
    if (id < 768)       { W = Wq; thi = Thi;           K = 512;  N = 1536; nt = 48; }
    else if (id < 1024) { W = Wa; thi = Thi + 786432;  K = 512;  N = 512;  nt = 16; id -= 768; }
    else if (id < 2048) { W = W1; thi = Thi + 1048576; K = 512;  N = 2048; nt = 64; id -= 1024; }
    else                { W = W2; thi = Thi + 2097152; K = 2048; N = 512;  nt = 16; id -= 2048; }
    int n0 = (id % nt) * 32, k0 = (id / nt) * 32;
    int tx = threadIdx.x & 31, ty = threadIdx.x >> 5;   // 32 x 8
#pragma unroll
    for (int i = 0; i < 4; i++) {
        int k = k0 + ty + i * 8;
        tile[ty + i * 8][tx] = W[(size_t)k * N + n0 + tx];
    }
    __syncthreads();
#pragma unroll
    for (int i = 0; i < 4; i++) {
        int n = n0 + ty + i * 8;
        thi[(size_t)n * K + k0 + tx] = f16hi(tile[tx][ty + i * 8]);
    }
}

// ---------------------------------------------------------------------------
// MFMA GEMM, templated tile 32FM x 32FN x 64, 4 waves.
// TP=true : C = (A_hi + A_lo) x B_hi  (2-pass: attn-fc, ff2 — the residual
//           writers, where error compounds linearly across layers).
// TP=false: C = A_hi x B_hi           (1-pass: qkv, ff1, vocab).
// Round-6 structure otherwise: single-buffered LDS, {barrier; stage;
// barrier; compute} per K-step, global_load_lds staging, linear LDS dest +
// inverse-swizzled global source col; reads byte ^= (row&7)<<4.
// F_XCDM (vocab): xcd = p&7 owns 4 m-tiles, n streams fastest (round-6 best).
// F_QKV epilogue: Q hi [bh][t][64], K hi [bh][t][64], V hi transposed
// [bh][64][t] (3 planes, feeds MFMA flash directly).
// ---------------------------------------------------------------------------
#define F_GELU  1
#define F_RES   2
#define F_SPLIT 4
#define F_QKV   8
#define F_XCDM  16

template<int FM, int FN, bool TP>
__global__ __launch_bounds__(256, 2)
void mfma_gemm_t(const u16* __restrict__ Ahi, const u16* __restrict__ Alo,
                 const u16* __restrict__ Bhi,
                 const float* __restrict__ bias, const float* __restrict__ res,
                 float* __restrict__ C, u16* __restrict__ Chi, u16* __restrict__ Clo,
                 u16* __restrict__ qkvp, int N, int K, int flags) {
    constexpr int TBM = 32 * FM, TBN = 32 * FN;
    constexpr int AP  = TP ? 2 : 1;
    __shared__ __align__(16) u16 ldsA[AP][TBM][64];
    __shared__ __align__(16) u16 ldsB[TBN][64];
    const int tid = threadIdx.x;

    // ---- block -> (m0, n0) ----
    int m0, n0;
    if (flags & F_XCDM) {
        int p    = blockIdx.y * (int)gridDim.x + blockIdx.x;
        int xcd  = p & 7;
        int i    = p >> 3;              // 0..999 within XCD
        int mloc = i / 250;             // 0..3 (n fastest within chunk)
        m0 = (xcd * 4 + mloc) * TBM;
        n0 = (i - mloc * 250) * TBN;
    } else {
        m0 = blockIdx.y * TBM;
        n0 = blockIdx.x * TBN;
    }

    const int wave = tid >> 6;
    const int lane = tid & 63;
    const int wr   = (wave >> 1) * 16 * FM;
    const int wc   = (wave & 1) * 16 * FN;
    const int lr   = lane & 15;
    const int lk   = lane >> 4;

    const int srow = wave * 8 + (lane >> 3);
    const int scol = ((lane & 7) ^ (lane >> 3)) * 8;   // inverse read swizzle
    const u16* As0 = Ahi + (size_t)(m0 + srow) * K + scol;
    const u16* As1 = nullptr;
    if constexpr (TP) As1 = Alo + (size_t)(m0 + srow) * K + scol;
    const u16* Bs0 = Bhi + (size_t)(n0 + srow) * K + scol;

    f32x4 acc[FM][FN] = {};

    for (int k0 = 0; k0 < K; k0 += 64) {
        __syncthreads();                 // previous tile's compute done
#pragma unroll
        for (int q = 0; q < FM; q++) {
            gload_lds16(As0 + (size_t)q * 32 * K + k0, &ldsA[0][q * 32 + wave * 8][0]);
            if constexpr (TP)
                gload_lds16(As1 + (size_t)q * 32 * K + k0, &ldsA[AP - 1][q * 32 + wave * 8][0]);
        }
#pragma unroll
        for (int q = 0; q < FN; q++) {
            gload_lds16(Bs0 + (size_t)q * 32 * K + k0, &ldsB[q * 32 + wave * 8][0]);
        }
        __syncthreads();                 // drains vmcnt(0) before barrier
#pragma unroll
        for (int ks = 0; ks < 2; ks++) {
            f16x8 ah[FM], al[FM], bhf[FN];
            const int koff = ks * 64 + lk * 16;
#pragma unroll
            for (int f = 0; f < FM; f++) {
                int arow = wr + f * 16 + lr;
                int aoff = koff ^ ((arow & 7) << 4);
                ah[f] = *(const f16x8*)((const char*)(&ldsA[0][arow][0]) + aoff);
                if constexpr (TP)
                    al[f] = *(const f16x8*)((const char*)(&ldsA[AP - 1][arow][0]) + aoff);
            }
#pragma unroll
            for (int f = 0; f < FN; f++) {
                int brow = wc + f * 16 + lr;
                int boff = koff ^ ((brow & 7) << 4);
                bhf[f] = *(const f16x8*)((const char*)(&ldsB[brow][0]) + boff);
            }
#pragma unroll
            for (int mf = 0; mf < FM; mf++)
#pragma unroll
                for (int nf = 0; nf < FN; nf++) {
                    acc[mf][nf] = __builtin_amdgcn_mfma_f32_16x16x32_f16(ah[mf], bhf[nf], acc[mf][nf], 0, 0, 0);
                    if constexpr (TP)
                        acc[mf][nf] = __builtin_amdgcn_mfma_f32_16x16x32_f16(al[mf], bhf[nf], acc[mf][nf], 0, 0, 0);
                }
        }
    }

    // ---- epilogue ----
#pragma unroll
    for (int mf = 0; mf < FM; mf++) {
#pragma unroll
        for (int nf = 0; nf < FN; nf++) {
            int col = n0 + wc + nf * 16 + lr;
            float bv = bias[col];
            float cv[4];
            int t0 = m0 + wr + mf * 16 + lk * 4;
#pragma unroll
            for (int r = 0; r < 4; r++) {
                float c = acc[mf][nf][r] + bv;
                if (flags & F_GELU) c = 0.5f * c * (1.0f + erff(c * 0.7071067811865476f));
                if (flags & F_RES)  c += res[(size_t)(t0 + r) * N + col];
                cv[r] = c;
            }
            if (flags & F_QKV) {
                // col -> (section, head, dh); row -> (b, t)
                int sect = col >> 9, hh = (col >> 6) & 7, dh = col & 63;
                int bb = t0 >> 11, tt = t0 & 2047;
                size_t bh = (size_t)bb * 8 + hh;
                if (sect == 2) {         // V hi, transposed: [bh][64][t]
                    ushort4 h4;
                    h4.x = f16hi(cv[0]); h4.y = f16hi(cv[1]);
                    h4.z = f16hi(cv[2]); h4.w = f16hi(cv[3]);
                    size_t vi = (bh * 64 + dh) * T_ + tt;
                    *(ushort4*)(qkvp + 2 * (size_t)PL_ + vi) = h4;
                } else {                 // Q hi (plane 0) or K hi (plane 1)
                    u16* dst = qkvp + (size_t)sect * PL_;
#pragma unroll
                    for (int r = 0; r < 4; r++) {
                        size_t qi = (bh * T_ + tt + r) * 64 + dh;
                        dst[qi] = f16hi(cv[r]);
                    }
                }
            } else if (flags & F_SPLIT) {
#pragma unroll
                for (int r = 0; r < 4; r++) {
                    u16 hi, lo; split_f16(cv[r], hi, lo);
                    Chi[(size_t)(t0 + r) * N + col] = hi;
                    Clo[(size_t)(t0 + r) * N + col] = lo;
                }
            } else {
#pragma unroll
                for (int r = 0; r < 4; r++)
                    C[(size_t)(t0 + r) * N + col] = cv[r];
            }
        }
    }
}

// ---------------------------------------------------------------------------
// MFMA causal flash attention, fp16, paired K/V staging (round-13) with
// 1-pass Q (round-14): S = Q_hi x K_hi (8 MFMA/subtile), O += P x V_hi.
// LDS 48 KB (Q + K[2] + V[2] + P) -> 3 blocks/CU (was 2).
// Block = (qt, bh); 4 waves, wave w owns q rows [w*16, +16) x all 64 keys.
// Balanced mapping: ids u and u+256 get complementary qt (i, 31-i).
// O written as hi+lo (attn-fc keeps 2-pass A).
// ---------------------------------------------------------------------------
__global__ __launch_bounds__(256)
void flash_mfma_kernel(const u16* __restrict__ qkvp,
                       u16* __restrict__ ohi, u16* __restrict__ olo) {
    const u16* qhp = qkvp;
    const u16* khp = qkvp + (size_t)PL_;
    const u16* vhp = qkvp + 2 * (size_t)PL_;

    __shared__ __align__(16) u16 Qs[64][64];
    __shared__ __align__(16) u16 Ks[2][64][64];   // [subtile][key][dh]
    __shared__ __align__(16) u16 Vs[2][64][64];   // [subtile][dh][key]
    __shared__ __align__(16) u16 Ps[64][64];

    // balanced (qt, bh) from flat id: u and u+256 -> (i, 31-i)
    const int u    = blockIdx.x;       // 0..511
    const int r0   = u & 255;
    const int bh   = r0 & 15;          // b*H + head
    const int i0   = r0 >> 4;          // 0..15
    const int qt   = (u >> 8) ? (31 - i0) : i0;

    const int tid = threadIdx.x;
    const int w = tid >> 6, lane = tid & 63;
    const int lr = lane & 15, lk = lane >> 4;

    const int srow = w * 8 + (lane >> 3);
    const int scol = ((lane & 7) ^ (lane >> 3)) * 8;

    // stage Q once (drained by first loop barrier pair)
    {
        size_t qb = ((size_t)bh * T_ + qt * 64 + srow) * 64 + scol;
#pragma unroll
        for (int q = 0; q < 2; q++)
            gload_lds16(qhp + qb + (size_t)q * 32 * 64, &Qs[q * 32 + w * 8][0]);
    }

    f32x4 accO[4] = {};
    float lsum[4] = {0.f, 0.f, 0.f, 0.f};

    auto stageKV = [&](int kt, int s) {
        size_t kb = ((size_t)bh * T_ + kt * 64 + srow) * 64 + scol;
        size_t vb = ((size_t)bh * 64 + srow) * T_ + (size_t)kt * 64 + scol;
#pragma unroll
        for (int q = 0; q < 2; q++) {
            gload_lds16(khp + kb + (size_t)q * 32 * 64, &Ks[s][q * 32 + w * 8][0]);
            gload_lds16(vhp + vb + (size_t)q * 32 * T_, &Vs[s][q * 32 + w * 8][0]);
        }
    };

    auto compute = [&](int kt, int s) {
        // ---- S = Q K^T, 1-pass: wave rows [w*16, +16), all 64 keys ----
        f32x4 accS[4] = {};
#pragma unroll
        for (int ks = 0; ks < 2; ks++) {
            const int koff = ks * 64 + lk * 16;
            const int arow = w * 16 + lr;
            const int aoff = koff ^ ((arow & 7) << 4);
            f16x8 qh = *(const f16x8*)((const char*)(&Qs[arow][0]) + aoff);
#pragma unroll
            for (int nf = 0; nf < 4; nf++) {
                int brow = nf * 16 + lr;
                int boff = koff ^ ((brow & 7) << 4);
                f16x8 kh = *(const f16x8*)((const char*)(&Ks[s][brow][0]) + boff);
                accS[nf] = __builtin_amdgcn_mfma_f32_16x16x32_f16(qh, kh, accS[nf], 0, 0, 0);
            }
        }

        // ---- mask + exp + P->fp16 LDS + row-sum partials ----
        const bool edge = (kt == qt);
#pragma unroll
        for (int nf = 0; nf < 4; nf++) {
            int keyl = nf * 16 + lr;
#pragma unroll
            for (int r = 0; r < 4; r++) {
                int rowl = lk * 4 + r;             // within wave's 16 rows
                float sv = accS[nf][r] * 0.125f;
                float p = (!edge || keyl <= w * 16 + rowl) ? __expf(sv) : 0.f;
                lsum[r] += p;
                int row = w * 16 + rowl;
                *(u16*)((char*)(&Ps[0][0]) + row * 128 + ((keyl * 2) ^ ((row & 7) << 4))) = f16hi(p);
            }
        }

        // ---- O += P V_hi (1-pass). P rows are same-wave (lgkm orders). ----
#pragma unroll
        for (int kk = 0; kk < 2; kk++) {
            const int koff = kk * 64 + lk * 16;
            const int arow = w * 16 + lr;
            f16x8 pa = *(const f16x8*)((const char*)(&Ps[0][0]) + arow * 128
                                       + (koff ^ ((arow & 7) << 4)));
#pragma unroll
            for (int nf = 0; nf < 4; nf++) {
                int brow = nf * 16 + lr;
                int boff = koff ^ ((brow & 7) << 4);
                f16x8 vh = *(const f16x8*)((const char*)(&Vs[s][brow][0]) + boff);
                accO[nf] = __builtin_amdgcn_mfma_f32_16x16x32_f16(pa, vh, accO[nf], 0, 0, 0);
            }
        }
    };

    for (int ktp = 0; ktp <= qt; ktp += 2) {
        const bool two = (ktp + 1 <= qt);
        __syncthreads();               // all waves done reading prev K/V
        stageKV(ktp, 0);
        if (two) stageKV(ktp + 1, 1);
        __syncthreads();               // staging drained (vmcnt 0)
        compute(ktp, 0);
        if (two) compute(ktp + 1, 1);
    }

    // ---- finish: reduce row sums over the 16-lane col group, write O ----
#pragma unroll
    for (int r = 0; r < 4; r++) {
        float v = lsum[r];
        v += __shfl_xor(v, 1, 64); v += __shfl_xor(v, 2, 64);
        v += __shfl_xor(v, 4, 64); v += __shfl_xor(v, 8, 64);
        lsum[r] = v;
    }
    const int b = bh >> 3, hd = bh & 7;
#pragma unroll
    for (int nf = 0; nf < 4; nf++) {
#pragma unroll
        for (int r = 0; r < 4; r++) {
            float val = accO[nf][r] / lsum[r];
            u16 hi, lo; split_f16(val, hi, lo);
            size_t idx = ((size_t)(b * T_ + qt * 64 + w * 16 + lk * 4 + r)) * D_
                         + hd * 64 + nf * 16 + lr;
            ohi[idx] = hi;
            olo[idx] = lo;
        }
    }
}

// ---------------------------------------------------------------------------
extern "C" void kernel_launch(void* const* d_in, const int* in_sizes, int n_in,
                              void* d_out, int out_size, void* d_ws, size_t ws_size,
                              hipStream_t stream) {
    const int*   x    = (const int*)   d_in[0];
    const float* emb  = (const float*) d_in[1];
    const float* ln1s = (const float*) d_in[2];
    const float* ln1b = (const float*) d_in[3];
    const float* qkvw = (const float*) d_in[4];
    const float* qkvb = (const float*) d_in[5];
    const float* afw  = (const float*) d_in[6];
    const float* afb  = (const float*) d_in[7];
    const float* ln2s = (const float*) d_in[8];
    const float* ln2b = (const float*) d_in[9];
    const float* fw1  = (const float*) d_in[10];
    const float* fb1  = (const float*) d_in[11];
    const float* fw2  = (const float*) d_in[12];
    const float* fb2  = (const float*) d_in[13];
    const float* lnfs = (const float*) d_in[14];
    const float* lnfb = (const float*) d_in[15];
    const float* fcw  = (const float*) d_in[16];
    const float* fcb  = (const float*) d_in[17];
    float* out = (float*)d_out;

    // Workspace (~106 MB):
    //  h        [M,D]  fp32                         8.39 MB
    //  yhi      [M,D]  fp16 plane                   4.19 MB
    //  atthi/lo [M,D]  fp16 planes                  8.39 MB
    //  qkvp     3 planes (Qhi,Khi,VThi)            12.58 MB
    //  ffhi/lo  [M,FF] fp16 planes                 33.55 MB
    //  Whi      per-layer weight hi slot (WL_)      6.29 MB
    //  WhiF     fc weight hi plane                 32.77 MB
    float* h     = (float*)d_ws;
    u16*   yhi   = (u16*)(h + (size_t)M_ * D_);
    u16*   atthi = yhi   + (size_t)M_ * D_;
    u16*   attlo = atthi + (size_t)M_ * D_;
    u16*   qkvp  = attlo + (size_t)M_ * D_;     // 3 * PL_ u16
    u16*   ffhi  = qkvp  + 3 * (size_t)PL_;
    u16*   fflo  = ffhi  + (size_t)M_ * FF_;
    u16*   Whi   = fflo  + (size_t)M_ * FF_;
    u16*   WhiF  = Whi   + WL_;

    // per-layer offsets inside the weight slot (elements)
    const size_t oq = 0, oa = 786432, of1 = 1048576, of2 = 2097152;

    embed_pe_kernel<<<M_, 128, 0, stream>>>(x, emb, h);

    for (int l = 0; l < L_; l++) {
        transpose_split4_kernel<<<3072, 256, 0, stream>>>(
            qkvw + (size_t)l * D_ * 3 * D_, afw + (size_t)l * D_ * D_,
            fw1 + (size_t)l * D_ * FF_, fw2 + (size_t)l * FF_ * D_, Whi);

        layernorm_kernel<<<M_ / 8, 512, 0, stream>>>(h, ln1s + l * D_, ln1b + l * D_, yhi);
        // qkv: N=1536, 64^2 tiles, 1-PASS A, head-separated output (F_QKV)
        mfma_gemm_t<2, 2, false><<<dim3(3 * D_ / 64, M_ / 64), 256, 0, stream>>>(
            yhi, nullptr, Whi + oq, qkvb + l * 3 * D_,
            nullptr, nullptr, nullptr, nullptr, qkvp, 3 * D_, D_, F_QKV);
        // flash: 1-D grid, balanced (qt,bh) pairing, paired staging, 1-pass Q
        flash_mfma_kernel<<<(T_ / 64) * B_ * H_, 256, 0, stream>>>(qkvp, atthi, attlo);
        // attn-fc: residual writer -> 2-PASS A
        mfma_gemm_t<2, 2, true><<<dim3(D_ / 64, M_ / 64), 256, 0, stream>>>(
            atthi, attlo, Whi + oa, afb + l * D_,
            h, h, nullptr, nullptr, nullptr, D_, D_, F_RES);
        layernorm_kernel<<<M_ / 8, 512, 0, stream>>>(h, ln2s + l * D_, ln2b + l * D_, yhi);
        // ff1: N=2048, 128^2 tiles, 1-PASS A
        mfma_gemm_t<4, 4, false><<<dim3(FF_ / 128, M_ / 128), 256, 0, stream>>>(
            yhi, nullptr, Whi + of1, fb1 + l * FF_,
            nullptr, nullptr, ffhi, fflo, nullptr, FF_, D_, F_GELU | F_SPLIT);
        // ff2: residual writer -> 2-PASS A
        mfma_gemm_t<2, 2, true><<<dim3(D_ / 64, M_ / 64), 256, 0, stream>>>(
            ffhi, fflo, Whi + of2, fb2 + l * D_,
            h, h, nullptr, nullptr, nullptr, D_, FF_, F_RES);
    }

    transpose_split_kernel<<<dim3(V_ / 32, D_ / 32), dim3(32, 8), 0, stream>>>(
        fcw, WhiF, D_, V_);
    layernorm_kernel<<<M_ / 8, 512, 0, stream>>>(h, lnfs, lnfb, yhi);
    // vocab: 128^2 tiles, F_XCDM mapping, 1-PASS A
    mfma_gemm_t<4, 4, false><<<dim3(V_ / 128, M_ / 128), 256, 0, stream>>>(
        yhi, nullptr, WhiF, fcb, nullptr, out, nullptr, nullptr, nullptr,
        V_, D_, F_XCDM);
}

// Round 15
// 1789.167 us; speedup vs baseline: 1.4824x; 1.1258x over previous
//
#include <hip/hip_runtime.h>
#include <math.h>

typedef unsigned short u16;
typedef unsigned int   u32;

// Problem constants (GPT reference)
#define V_  32000
#define D_  512
#define H_  8
#define DH_ 64
#define L_  8
#define FF_ 2048
#define B_  2
#define T_  2048
#define M_  (B_*T_)   // 4096 token rows

typedef __attribute__((ext_vector_type(8))) _Float16 f16x8;  // 8 fp16 = 4 VGPR
typedef __attribute__((ext_vector_type(4))) float    f32x4;

#define PL_ 2097152    // elements per Q/K/V plane: B*H*T*DH = 16*2048*64
#define WL_ 3145728ull // weight hi-plane elements per layer (qkv+af+ff1+ff2)

// Uniform 1-pass fp16 numerics (empirically validated, rounds 12-14):
// absmax invariant at 0.015625 across (a) B-side 2^-11 rounding on EVERY
// GEMM incl. the residual writers, (b) vocab/qkv/ff1/Q A_lo drops. Rounding
// A vs B is symmetric in output-error magnitude (|A||B| 2^-11 sqrt(K)), so
// round 15 mirrors (a) on the A side of attn-fc/ff2. All accumulation and
// all residual/bias/GELU epilogues remain fp32.
__device__ inline u16 f16hi(float x) {
    _Float16 h = (_Float16)x;
    return __builtin_bit_cast(u16, h);
}

// Async global->LDS, 16B per lane. LDS dest = wave-uniform base + lane*16
// (HW behavior, m104/m108); global src is per-lane.
__device__ inline void gload_lds16(const u16* g, u16* l) {
    __builtin_amdgcn_global_load_lds(
        (__attribute__((address_space(1))) void*)(void*)const_cast<u16*>(g),
        (__attribute__((address_space(3))) void*)(void*)l, 16, 0, 0);
}

// ---------------------------------------------------------------------------
// Embedding + positional encoding: h[row,d] = emb[x[row],d] + pe(t,d), fp32
// ---------------------------------------------------------------------------
__global__ void embed_pe_kernel(const int* __restrict__ x,
                                const float* __restrict__ emb,
                                float* __restrict__ h) {
    int row = blockIdx.x;          // 0..M_-1 ; row = b*T + t
    int t   = row % T_;
    int tok = x[row];
    const float* er = emb + (size_t)tok * D_;
    for (int d = threadIdx.x; d < D_; d += blockDim.x) {
        int i = d >> 1;
        float freq = expf((float)(2 * i) * (-9.210340371976184f / (float)D_));
        float ang  = (float)t * freq;
        float pe   = (d & 1) ? cosf(ang) : sinf(ang);
        h[(size_t)row * D_ + d] = er[d] + pe;
    }
}

// ---------------------------------------------------------------------------
// LayerNorm: one wave per row of D=512, 8 waves per block (512 threads).
// fp32 in, fp16 hi plane out.
// ---------------------------------------------------------------------------
__global__ __launch_bounds__(512)
void layernorm_kernel(const float* __restrict__ xin,
                      const float* __restrict__ scale,
                      const float* __restrict__ bias,
                      u16* __restrict__ yhi) {
    int row  = blockIdx.x * 8 + (threadIdx.x >> 6);
    int lane = threadIdx.x & 63;   // 0..63
    const float* xr = xin + (size_t)row * D_;
    float v[8];
    float s = 0.f;
#pragma unroll
    for (int i = 0; i < 8; i++) { v[i] = xr[i * 64 + lane]; s += v[i]; }
#pragma unroll
    for (int off = 32; off; off >>= 1) s += __shfl_xor(s, off, 64);
    float mu = s * (1.0f / D_);
    float var = 0.f;
#pragma unroll
    for (int i = 0; i < 8; i++) { float d0 = v[i] - mu; var += d0 * d0; }
#pragma unroll
    for (int off = 32; off; off >>= 1) var += __shfl_xor(var, off, 64);
    var *= (1.0f / D_);
    float r = rsqrtf(var + 1e-5f);
#pragma unroll
    for (int i = 0; i < 8; i++) {
        int d0 = i * 64 + lane;
        float val = (v[i] - mu) * r * scale[d0] + bias[d0];
        yhi[(size_t)row * D_ + d0] = f16hi(val);
    }
}

// ---------------------------------------------------------------------------
// Weight transpose + fp16 hi: W[K][N] fp32 -> Thi [N][K] fp16 plane.
// Generic single-matrix version (used for fc_w).
// ---------------------------------------------------------------------------
__global__ __launch_bounds__(256)
void transpose_split_kernel(const float* __restrict__ W,
                            u16* __restrict__ Thi, int K, int N) {
    __shared__ float tile[32][33];
    int n0 = blockIdx.x * 32, k0 = blockIdx.y * 32;
    int tx = threadIdx.x, ty = threadIdx.y;   // 32 x 8
#pragma unroll
    for (int i = 0; i < 4; i++) {
        int k = k0 + ty + i * 8;
        tile[ty + i * 8][tx] = W[(size_t)k * N + n0 + tx];   // coalesced in n
    }
    __syncthreads();
#pragma unroll
    for (int i = 0; i < 4; i++) {
        int n = n0 + ty + i * 8;
        Thi[(size_t)n * K + k0 + tx] = f16hi(tile[tx][ty + i * 8]);
    }
}

// ---------------------------------------------------------------------------
// Fused per-layer transpose: all 4 weight matrices in one launch (round-6
// proven placement: per-layer launch keeps the hot slot L2/L3-warm).
// ---------------------------------------------------------------------------
__global__ __launch_bounds__(256)
void transpose_split4_kernel(const float* __restrict__ Wq, const float* __restrict__ Wa,
                             const float* __restrict__ W1, const float* __restrict__ W2,
                             u16* __restrict__ Thi) {
    __shared__ float tile[32][33];
    int id = blockIdx.x;
    const float* W; u16 *thi; int K, N, nt;
    if (id < 768)       { W = Wq; thi = Thi;           K = 512;  N = 1536; nt = 48; }
    else if (id < 1024) { W = Wa; thi = Thi + 786432;  K = 512;  N = 512;  nt = 16; id -= 768; }
    else if (id < 2048) { W = W1; thi = Thi + 1048576; K = 512;  N = 2048; nt = 64; id -= 1024; }
    else                { W = W2; thi = Thi + 2097152; K = 2048; N = 512;  nt = 16; id -= 2048; }
    int n0 = (id % nt) * 32, k0 = (id / nt) * 32;
    int tx = threadIdx.x & 31, ty = threadIdx.x >> 5;   // 32 x 8
#pragma unroll
    for (int i = 0; i < 4; i++) {
        int k = k0 + ty + i * 8;
        tile[ty + i * 8][tx] = W[(size_t)k * N + n0 + tx];
    }
    __syncthreads();
#pragma unroll
    for (int i = 0; i < 4; i++) {
        int n = n0 + ty + i * 8;
        thi[(size_t)n * K + k0 + tx] = f16hi(tile[tx][ty + i * 8]);
    }
}

// ---------------------------------------------------------------------------
// MFMA GEMM, templated tile 32FM x 32FN x 64, 4 waves, uniform 1-pass fp16:
// C = A_hi x B_hi, fp32 accumulate + fp32 epilogue.
// Round-6 structure: single-buffered LDS, {barrier; stage; barrier; compute}
// per K-step, global_load_lds staging, linear LDS dest + inverse-swizzled
// global source col; reads byte ^= (row&7)<<4. LDS: <4,4> 32 KB, <2,2> 16 KB.
// F_XCDM (vocab): xcd = p&7 owns 4 m-tiles, n streams fastest (round-6 best).
// F_QKV epilogue: Q hi [bh][t][64], K hi [bh][t][64], V hi transposed
// [bh][64][t] (3 planes, feeds MFMA flash directly).
// F_HI: fp16 hi plane output (ff1 -> ffhi).
// ---------------------------------------------------------------------------
#define F_GELU  1
#define F_RES   2
#define F_HI    4
#define F_QKV   8
#define F_XCDM  16

template<int FM, int FN>
__global__ __launch_bounds__(256, 2)
void mfma_gemm_t(const u16* __restrict__ Ahi, const u16* __restrict__ Bhi,
                 const float* __restrict__ bias, const float* __restrict__ res,
                 float* __restrict__ C, u16* __restrict__ Chi,
                 u16* __restrict__ qkvp, int N, int K, int flags) {
    constexpr int TBM = 32 * FM, TBN = 32 * FN;
    __shared__ __align__(16) u16 ldsA[TBM][64];
    __shared__ __align__(16) u16 ldsB[TBN][64];
    const int tid = threadIdx.x;

    // ---- block -> (m0, n0) ----
    int m0, n0;
    if (flags & F_XCDM) {
        int p    = blockIdx.y * (int)gridDim.x + blockIdx.x;
        int xcd  = p & 7;
        int i    = p >> 3;              // 0..999 within XCD
        int mloc = i / 250;             // 0..3 (n fastest within chunk)
        m0 = (xcd * 4 + mloc) * TBM;
        n0 = (i - mloc * 250) * TBN;
    } else {
        m0 = blockIdx.y * TBM;
        n0 = blockIdx.x * TBN;
    }

    const int wave = tid >> 6;
    const int lane = tid & 63;
    const int wr   = (wave >> 1) * 16 * FM;
    const int wc   = (wave & 1) * 16 * FN;
    const int lr   = lane & 15;
    const int lk   = lane >> 4;

    const int srow = wave * 8 + (lane >> 3);
    const int scol = ((lane & 7) ^ (lane >> 3)) * 8;   // inverse read swizzle
    const u16* As0 = Ahi + (size_t)(m0 + srow) * K + scol;
    const u16* Bs0 = Bhi + (size_t)(n0 + srow) * K + scol;

    f32x4 acc[FM][FN] = {};

    for (int k0 = 0; k0 < K; k0 += 64) {
        __syncthreads();                 // previous tile's compute done
#pragma unroll
        for (int q = 0; q < FM; q++)
            gload_lds16(As0 + (size_t)q * 32 * K + k0, &ldsA[q * 32 + wave * 8][0]);
#pragma unroll
        for (int q = 0; q < FN; q++)
            gload_lds16(Bs0 + (size_t)q * 32 * K + k0, &ldsB[q * 32 + wave * 8][0]);
        __syncthreads();                 // drains vmcnt(0) before barrier
#pragma unroll
        for (int ks = 0; ks < 2; ks++) {
            f16x8 ah[FM], bhf[FN];
            const int koff = ks * 64 + lk * 16;
#pragma unroll
            for (int f = 0; f < FM; f++) {
                int arow = wr + f * 16 + lr;
                int aoff = koff ^ ((arow & 7) << 4);
                ah[f] = *(const f16x8*)((const char*)(&ldsA[arow][0]) + aoff);
            }
#pragma unroll
            for (int f = 0; f < FN; f++) {
                int brow = wc + f * 16 + lr;
                int boff = koff ^ ((brow & 7) << 4);
                bhf[f] = *(const f16x8*)((const char*)(&ldsB[brow][0]) + boff);
            }
#pragma unroll
            for (int mf = 0; mf < FM; mf++)
#pragma unroll
                for (int nf = 0; nf < FN; nf++)
                    acc[mf][nf] = __builtin_amdgcn_mfma_f32_16x16x32_f16(ah[mf], bhf[nf], acc[mf][nf], 0, 0, 0);
        }
    }

    // ---- epilogue ----
#pragma unroll
    for (int mf = 0; mf < FM; mf++) {
#pragma unroll
        for (int nf = 0; nf < FN; nf++) {
            int col = n0 + wc + nf * 16 + lr;
            float bv = bias[col];
            float cv[4];
            int t0 = m0 + wr + mf * 16 + lk * 4;
#pragma unroll
            for (int r = 0; r < 4; r++) {
                float c = acc[mf][nf][r] + bv;
                if (flags & F_GELU) c = 0.5f * c * (1.0f + erff(c * 0.7071067811865476f));
                if (flags & F_RES)  c += res[(size_t)(t0 + r) * N + col];
                cv[r] = c;
            }
            if (flags & F_QKV) {
                // col -> (section, head, dh); row -> (b, t)
                int sect = col >> 9, hh = (col >> 6) & 7, dh = col & 63;
                int bb = t0 >> 11, tt = t0 & 2047;
                size_t bh = (size_t)bb * 8 + hh;
                if (sect == 2) {         // V hi, transposed: [bh][64][t]
                    ushort4 h4;
                    h4.x = f16hi(cv[0]); h4.y = f16hi(cv[1]);
                    h4.z = f16hi(cv[2]); h4.w = f16hi(cv[3]);
                    size_t vi = (bh * 64 + dh) * T_ + tt;
                    *(ushort4*)(qkvp + 2 * (size_t)PL_ + vi) = h4;
                } else {                 // Q hi (plane 0) or K hi (plane 1)
                    u16* dst = qkvp + (size_t)sect * PL_;
#pragma unroll
                    for (int r = 0; r < 4; r++) {
                        size_t qi = (bh * T_ + tt + r) * 64 + dh;
                        dst[qi] = f16hi(cv[r]);
                    }
                }
            } else if (flags & F_HI) {
#pragma unroll
                for (int r = 0; r < 4; r++)
                    Chi[(size_t)(t0 + r) * N + col] = f16hi(cv[r]);
            } else {
#pragma unroll
                for (int r = 0; r < 4; r++)
                    C[(size_t)(t0 + r) * N + col] = cv[r];
            }
        }
    }
}

// ---------------------------------------------------------------------------
// MFMA causal flash attention, fp16 1-pass, paired K/V staging (round-13):
// S = Q_hi x K_hi, O += P x V_hi. LDS 48 KB (Q + K[2] + V[2] + P).
// Block = (qt, bh); 4 waves, wave w owns q rows [w*16, +16) x all 64 keys.
// Balanced mapping: ids u and u+256 get complementary qt (i, 31-i).
// O written as fp16 hi (attn-fc is 1-pass).
// ---------------------------------------------------------------------------
__global__ __launch_bounds__(256)
void flash_mfma_kernel(const u16* __restrict__ qkvp, u16* __restrict__ ohi) {
    const u16* qhp = qkvp;
    const u16* khp = qkvp + (size_t)PL_;
    const u16* vhp = qkvp + 2 * (size_t)PL_;

    __shared__ __align__(16) u16 Qs[64][64];
    __shared__ __align__(16) u16 Ks[2][64][64];   // [subtile][key][dh]
    __shared__ __align__(16) u16 Vs[2][64][64];   // [subtile][dh][key]
    __shared__ __align__(16) u16 Ps[64][64];

    // balanced (qt, bh) from flat id: u and u+256 -> (i, 31-i)
    const int u    = blockIdx.x;       // 0..511
    const int r0   = u & 255;
    const int bh   = r0 & 15;          // b*H + head
    const int i0   = r0 >> 4;          // 0..15
    const int qt   = (u >> 8) ? (31 - i0) : i0;

    const int tid = threadIdx.x;
    const int w = tid >> 6, lane = tid & 63;
    const int lr = lane & 15, lk = lane >> 4;

    const int srow = w * 8 + (lane >> 3);
    const int scol = ((lane & 7) ^ (lane >> 3)) * 8;

    // stage Q once (drained by first loop barrier pair)
    {
        size_t qb = ((size_t)bh * T_ + qt * 64 + srow) * 64 + scol;
#pragma unroll
        for (int q = 0; q < 2; q++)
            gload_lds16(qhp + qb + (size_t)q * 32 * 64, &Qs[q * 32 + w * 8][0]);
    }

    f32x4 accO[4] = {};
    float lsum[4] = {0.f, 0.f, 0.f, 0.f};

    auto stageKV = [&](int kt, int s) {
        size_t kb = ((size_t)bh * T_ + kt * 64 + srow) * 64 + scol;
        size_t vb = ((size_t)bh * 64 + srow) * T_ + (size_t)kt * 64 + scol;
#pragma unroll
        for (int q = 0; q < 2; q++) {
            gload_lds16(khp + kb + (size_t)q * 32 * 64, &Ks[s][q * 32 + w * 8][0]);
            gload_lds16(vhp + vb + (size_t)q * 32 * T_, &Vs[s][q * 32 + w * 8][0]);
        }
    };

    auto compute = [&](int kt, int s) {
        // ---- S = Q K^T, 1-pass: wave rows [w*16, +16), all 64 keys ----
        f32x4 accS[4] = {};
#pragma unroll
        for (int ks = 0; ks < 2; ks++) {
            const int koff = ks * 64 + lk * 16;
            const int arow = w * 16 + lr;
            const int aoff = koff ^ ((arow & 7) << 4);
            f16x8 qh = *(const f16x8*)((const char*)(&Qs[arow][0]) + aoff);
#pragma unroll
            for (int nf = 0; nf < 4; nf++) {
                int brow = nf * 16 + lr;
                int boff = koff ^ ((brow & 7) << 4);
                f16x8 kh = *(const f16x8*)((const char*)(&Ks[s][brow][0]) + boff);
                accS[nf] = __builtin_amdgcn_mfma_f32_16x16x32_f16(qh, kh, accS[nf], 0, 0, 0);
            }
        }

        // ---- mask + exp + P->fp16 LDS + row-sum partials ----
        const bool edge = (kt == qt);
#pragma unroll
        for (int nf = 0; nf < 4; nf++) {
            int keyl = nf * 16 + lr;
#pragma unroll
            for (int r = 0; r < 4; r++) {
                int rowl = lk * 4 + r;             // within wave's 16 rows
                float sv = accS[nf][r] * 0.125f;
                float p = (!edge || keyl <= w * 16 + rowl) ? __expf(sv) : 0.f;
                lsum[r] += p;
                int row = w * 16 + rowl;
                *(u16*)((char*)(&Ps[0][0]) + row * 128 + ((keyl * 2) ^ ((row & 7) << 4))) = f16hi(p);
            }
        }

        // ---- O += P V_hi (1-pass). P rows are same-wave (lgkm orders). ----
#pragma unroll
        for (int kk = 0; kk < 2; kk++) {
            const int koff = kk * 64 + lk * 16;
            const int arow = w * 16 + lr;
            f16x8 pa = *(const f16x8*)((const char*)(&Ps[0][0]) + arow * 128
                                       + (koff ^ ((arow & 7) << 4)));
#pragma unroll
            for (int nf = 0; nf < 4; nf++) {
                int brow = nf * 16 + lr;
                int boff = koff ^ ((brow & 7) << 4);
                f16x8 vh = *(const f16x8*)((const char*)(&Vs[s][brow][0]) + boff);
                accO[nf] = __builtin_amdgcn_mfma_f32_16x16x32_f16(pa, vh, accO[nf], 0, 0, 0);
            }
        }
    };

    for (int ktp = 0; ktp <= qt; ktp += 2) {
        const bool two = (ktp + 1 <= qt);
        __syncthreads();               // all waves done reading prev K/V
        stageKV(ktp, 0);
        if (two) stageKV(ktp + 1, 1);
        __syncthreads();               // staging drained (vmcnt 0)
        compute(ktp, 0);
        if (two) compute(ktp + 1, 1);
    }

    // ---- finish: reduce row sums over the 16-lane col group, write O ----
#pragma unroll
    for (int r = 0; r < 4; r++) {
        float v = lsum[r];
        v += __shfl_xor(v, 1, 64); v += __shfl_xor(v, 2, 64);
        v += __shfl_xor(v, 4, 64); v += __shfl_xor(v, 8, 64);
        lsum[r] = v;
    }
    const int b = bh >> 3, hd = bh & 7;
#pragma unroll
    for (int nf = 0; nf < 4; nf++) {
#pragma unroll
        for (int r = 0; r < 4; r++) {
            float val = accO[nf][r] / lsum[r];
            size_t idx = ((size_t)(b * T_ + qt * 64 + w * 16 + lk * 4 + r)) * D_
                         + hd * 64 + nf * 16 + lr;
            ohi[idx] = f16hi(val);
        }
    }
}

// ---------------------------------------------------------------------------
extern "C" void kernel_launch(void* const* d_in, const int* in_sizes, int n_in,
                              void* d_out, int out_size, void* d_ws, size_t ws_size,
                              hipStream_t stream) {
    const int*   x    = (const int*)   d_in[0];
    const float* emb  = (const float*) d_in[1];
    const float* ln1s = (const float*) d_in[2];
    const float* ln1b = (const float*) d_in[3];
    const float* qkvw = (const float*) d_in[4];
    const float* qkvb = (const float*) d_in[5];
    const float* afw  = (const float*) d_in[6];
    const float* afb  = (const float*) d_in[7];
    const float* ln2s = (const float*) d_in[8];
    const float* ln2b = (const float*) d_in[9];
    const float* fw1  = (const float*) d_in[10];
    const float* fb1  = (const float*) d_in[11];
    const float* fw2  = (const float*) d_in[12];
    const float* fb2  = (const float*) d_in[13];
    const float* lnfs = (const float*) d_in[14];
    const float* lnfb = (const float*) d_in[15];
    const float* fcw  = (const float*) d_in[16];
    const float* fcb  = (const float*) d_in[17];
    float* out = (float*)d_out;

    // Workspace (~85 MB):
    //  h     [M,D]  fp32                    8.39 MB
    //  yhi   [M,D]  fp16                    4.19 MB
    //  atthi [M,D]  fp16                    4.19 MB
    //  qkvp  3 planes (Qhi,Khi,VThi)       12.58 MB
    //  ffhi  [M,FF] fp16                   16.78 MB
    //  Whi   per-layer weight slot (WL_)    6.29 MB
    //  WhiF  fc weight plane               32.77 MB
    float* h     = (float*)d_ws;
    u16*   yhi   = (u16*)(h + (size_t)M_ * D_);
    u16*   atthi = yhi   + (size_t)M_ * D_;
    u16*   qkvp  = atthi + (size_t)M_ * D_;     // 3 * PL_ u16
    u16*   ffhi  = qkvp  + 3 * (size_t)PL_;
    u16*   Whi   = ffhi  + (size_t)M_ * FF_;
    u16*   WhiF  = Whi   + WL_;

    // per-layer offsets inside the weight slot (elements)
    const size_t oq = 0, oa = 786432, of1 = 1048576, of2 = 2097152;

    embed_pe_kernel<<<M_, 128, 0, stream>>>(x, emb, h);

    for (int l = 0; l < L_; l++) {
        transpose_split4_kernel<<<3072, 256, 0, stream>>>(
            qkvw + (size_t)l * D_ * 3 * D_, afw + (size_t)l * D_ * D_,
            fw1 + (size_t)l * D_ * FF_, fw2 + (size_t)l * FF_ * D_, Whi);

        layernorm_kernel<<<M_ / 8, 512, 0, stream>>>(h, ln1s + l * D_, ln1b + l * D_, yhi);
        // qkv: N=1536, 64^2 tiles, head-separated output (F_QKV)
        mfma_gemm_t<2, 2><<<dim3(3 * D_ / 64, M_ / 64), 256, 0, stream>>>(
            yhi, Whi + oq, qkvb + l * 3 * D_,
            nullptr, nullptr, nullptr, qkvp, 3 * D_, D_, F_QKV);
        // flash: 1-D grid, balanced (qt,bh) pairing, paired staging
        flash_mfma_kernel<<<(T_ / 64) * B_ * H_, 256, 0, stream>>>(qkvp, atthi);
        // attn-fc: N=512, 64^2 tiles -> 512 blocks, residual epilogue fp32
        mfma_gemm_t<2, 2><<<dim3(D_ / 64, M_ / 64), 256, 0, stream>>>(
            atthi, Whi + oa, afb + l * D_,
            h, h, nullptr, nullptr, D_, D_, F_RES);
        layernorm_kernel<<<M_ / 8, 512, 0, stream>>>(h, ln2s + l * D_, ln2b + l * D_, yhi);
        // ff1: N=2048, 128^2 tiles -> 512 blocks, fp16 hi out
        mfma_gemm_t<4, 4><<<dim3(FF_ / 128, M_ / 128), 256, 0, stream>>>(
            yhi, Whi + of1, fb1 + l * FF_,
            nullptr, nullptr, ffhi, nullptr, FF_, D_, F_GELU | F_HI);
        // ff2: N=512, K=2048 -> 512 blocks, residual epilogue fp32
        mfma_gemm_t<2, 2><<<dim3(D_ / 64, M_ / 64), 256, 0, stream>>>(
            ffhi, Whi + of2, fb2 + l * D_,
            h, h, nullptr, nullptr, D_, FF_, F_RES);
    }

    transpose_split_kernel<<<dim3(V_ / 32, D_ / 32), dim3(32, 8), 0, stream>>>(
        fcw, WhiF, D_, V_);
    layernorm_kernel<<<M_ / 8, 512, 0, stream>>>(h, lnfs, lnfb, yhi);
    // vocab: 128^2 tiles, F_XCDM mapping
    mfma_gemm_t<4, 4><<<dim3(V_ / 128, M_ / 128), 256, 0, stream>>>(
        yhi, WhiF, fcb, nullptr, out, nullptr, nullptr, V_, D_, F_XCDM);
}

// Round 16
// 1699.309 us; speedup vs baseline: 1.5608x; 1.0529x over previous
//
#include <hip/hip_runtime.h>
#include <math.h>

typedef unsigned short u16;
typedef unsigned int   u32;

// Problem constants (GPT reference)
#define V_  32000
#define D_  512
#define H_  8
#define DH_ 64
#define L_  8
#define FF_ 2048
#define B_  2
#define T_  2048
#define M_  (B_*T_)   // 4096 token rows

typedef __attribute__((ext_vector_type(8))) _Float16 f16x8;  // 8 fp16 = 4 VGPR
typedef __attribute__((ext_vector_type(4))) float    f32x4;

#define PL_ 2097152    // elements per Q/K/V plane: B*H*T*DH = 16*2048*64
#define WL_ 3145728ull // weight hi-plane elements per layer (qkv+af+ff1+ff2)

// Uniform 1-pass fp16 numerics (validated rounds 12-15: absmax invariant at
// 0.015625 across every precision perturbation). fp32 accumulate; fp32
// residual/bias/GELU epilogues.
__device__ inline u16 f16hi(float x) {
    _Float16 h = (_Float16)x;
    return __builtin_bit_cast(u16, h);
}

// Async global->LDS, 16B per lane. LDS dest = wave-uniform base + lane*16
// (HW behavior, m104/m108); global src is per-lane.
__device__ inline void gload_lds16(const u16* g, u16* l) {
    __builtin_amdgcn_global_load_lds(
        (__attribute__((address_space(1))) void*)(void*)const_cast<u16*>(g),
        (__attribute__((address_space(3))) void*)(void*)l, 16, 0, 0);
}

// ---------------------------------------------------------------------------
// Embedding + positional encoding: h[row,d] = emb[x[row],d] + pe(t,d), fp32
// ---------------------------------------------------------------------------
__global__ void embed_pe_kernel(const int* __restrict__ x,
                                const float* __restrict__ emb,
                                float* __restrict__ h) {
    int row = blockIdx.x;          // 0..M_-1 ; row = b*T + t
    int t   = row % T_;
    int tok = x[row];
    const float* er = emb + (size_t)tok * D_;
    for (int d = threadIdx.x; d < D_; d += blockDim.x) {
        int i = d >> 1;
        float freq = expf((float)(2 * i) * (-9.210340371976184f / (float)D_));
        float ang  = (float)t * freq;
        float pe   = (d & 1) ? cosf(ang) : sinf(ang);
        h[(size_t)row * D_ + d] = er[d] + pe;
    }
}

// ---------------------------------------------------------------------------
// LayerNorm: one wave per row of D=512, 8 waves per block (512 threads).
// fp32 in, fp16 hi plane out.
// ---------------------------------------------------------------------------
__global__ __launch_bounds__(512)
void layernorm_kernel(const float* __restrict__ xin,
                      const float* __restrict__ scale,
                      const float* __restrict__ bias,
                      u16* __restrict__ yhi) {
    int row  = blockIdx.x * 8 + (threadIdx.x >> 6);
    int lane = threadIdx.x & 63;   // 0..63
    const float* xr = xin + (size_t)row * D_;
    float v[8];
    float s = 0.f;
#pragma unroll
    for (int i = 0; i < 8; i++) { v[i] = xr[i * 64 + lane]; s += v[i]; }
#pragma unroll
    for (int off = 32; off; off >>= 1) s += __shfl_xor(s, off, 64);
    float mu = s * (1.0f / D_);
    float var = 0.f;
#pragma unroll
    for (int i = 0; i < 8; i++) { float d0 = v[i] - mu; var += d0 * d0; }
#pragma unroll
    for (int off = 32; off; off >>= 1) var += __shfl_xor(var, off, 64);
    var *= (1.0f / D_);
    float r = rsqrtf(var + 1e-5f);
#pragma unroll
    for (int i = 0; i < 8; i++) {
        int d0 = i * 64 + lane;
        float val = (v[i] - mu) * r * scale[d0] + bias[d0];
        yhi[(size_t)row * D_ + d0] = f16hi(val);
    }
}

// ---------------------------------------------------------------------------
// Weight transpose + fp16 hi: W[K][N] fp32 -> Thi [N][K] fp16 plane.
// Generic single-matrix version (used for fc_w).
// ---------------------------------------------------------------------------
__global__ __launch_bounds__(256)
void transpose_split_kernel(const float* __restrict__ W,
                            u16* __restrict__ Thi, int K, int N) {
    __shared__ float tile[32][33];
    int n0 = blockIdx.x * 32, k0 = blockIdx.y * 32;
    int tx = threadIdx.x, ty = threadIdx.y;   // 32 x 8
#pragma unroll
    for (int i = 0; i < 4; i++) {
        int k = k0 + ty + i * 8;
        tile[ty + i * 8][tx] = W[(size_t)k * N + n0 + tx];   // coalesced in n
    }
    __syncthreads();
#pragma unroll
    for (int i = 0; i < 4; i++) {
        int n = n0 + ty + i * 8;
        Thi[(size_t)n * K + k0 + tx] = f16hi(tile[tx][ty + i * 8]);
    }
}

// ---------------------------------------------------------------------------
// Fused per-layer transpose: all 4 weight matrices in one launch (round-6
// proven placement: per-layer launch keeps the hot slot L2/L3-warm).
// ---------------------------------------------------------------------------
__global__ __launch_bounds__(256)
void transpose_split4_kernel(const float* __restrict__ Wq, const float* __restrict__ Wa,
                             const float* __restrict__ W1, const float* __restrict__ W2,
                             u16* __restrict__ Thi) {
    __shared__ float tile[32][33];
    int id = blockIdx.x;
    const float* W; u16 *thi; int K, N, nt;
    if (id < 768)       { W = Wq; thi = Thi;           K = 512;  N = 1536; nt = 48; }
    else if (id < 1024) { W = Wa; thi = Thi + 786432;  K = 512;  N = 512;  nt = 16; id -= 768; }
    else if (id < 2048) { W = W1; thi = Thi + 1048576; K = 512;  N = 2048; nt = 64; id -= 1024; }
    else                { W = W2; thi = Thi + 2097152; K = 2048; N = 512;  nt = 16; id -= 2048; }
    int n0 = (id % nt) * 32, k0 = (id / nt) * 32;
    int tx = threadIdx.x & 31, ty = threadIdx.x >> 5;   // 32 x 8
#pragma unroll
    for (int i = 0; i < 4; i++) {
        int k = k0 + ty + i * 8;
        tile[ty + i * 8][tx] = W[(size_t)k * N + n0 + tx];
    }
    __syncthreads();
#pragma unroll
    for (int i = 0; i < 4; i++) {
        int n = n0 + ty + i * 8;
        thi[(size_t)n * K + k0 + tx] = f16hi(tile[tx][ty + i * 8]);
    }
}

// ---------------------------------------------------------------------------
// MFMA GEMM, templated tile 32FM x 32FN x 64, 4 waves, 1-pass fp16:
// C = A_hi x B_hi, fp32 accumulate + fp32 epilogue.
// Round-6 structure: single-buffered LDS, {barrier; stage; barrier; compute}
// per K-step, global_load_lds staging, linear LDS dest + inverse-swizzled
// global source col; reads byte ^= (row&7)<<4.
// ROUND-16 tiling (TLP for the latency-bound small-K GEMMs — only 8 K-steps,
// per-step time = drain latency; more resident blocks hide it):
//   attn-fc/ff2: <1,2> 32x64 tiles -> 1024 blocks, 12 KB LDS (4+ blocks/CU)
//   ff1:         <2,2> 64x64 tiles -> 2048 blocks, 16 KB LDS (8 blocks/CU)
//   qkv <2,2> (1536 blocks) and vocab <4,4> (compute-bound) unchanged.
// A-refetch volume is tile-size-invariant here (N/TBN constant); B panels
// are <=4 MB fp16, L2/L3-resident -> round-4's fetch blowup doesn't apply.
// F_XCDM (vocab): xcd = p&7 owns 4 m-tiles, n streams fastest.
// F_QKV epilogue: Q/K hi [bh][t][64], V hi transposed [bh][64][t].
// ---------------------------------------------------------------------------
#define F_GELU  1
#define F_RES   2
#define F_HI    4
#define F_QKV   8
#define F_XCDM  16

template<int FM, int FN>
__global__ __launch_bounds__(256, 2)
void mfma_gemm_t(const u16* __restrict__ Ahi, const u16* __restrict__ Bhi,
                 const float* __restrict__ bias, const float* __restrict__ res,
                 float* __restrict__ C, u16* __restrict__ Chi,
                 u16* __restrict__ qkvp, int N, int K, int flags) {
    constexpr int TBM = 32 * FM, TBN = 32 * FN;
    __shared__ __align__(16) u16 ldsA[TBM][64];
    __shared__ __align__(16) u16 ldsB[TBN][64];
    const int tid = threadIdx.x;

    // ---- block -> (m0, n0) ----
    int m0, n0;
    if (flags & F_XCDM) {
        int p    = blockIdx.y * (int)gridDim.x + blockIdx.x;
        int xcd  = p & 7;
        int i    = p >> 3;              // 0..999 within XCD
        int mloc = i / 250;             // 0..3 (n fastest within chunk)
        m0 = (xcd * 4 + mloc) * TBM;
        n0 = (i - mloc * 250) * TBN;
    } else {
        m0 = blockIdx.y * TBM;
        n0 = blockIdx.x * TBN;
    }

    const int wave = tid >> 6;
    const int lane = tid & 63;
    const int wr   = (wave >> 1) * 16 * FM;
    const int wc   = (wave & 1) * 16 * FN;
    const int lr   = lane & 15;
    const int lk   = lane >> 4;

    const int srow = wave * 8 + (lane >> 3);
    const int scol = ((lane & 7) ^ (lane >> 3)) * 8;   // inverse read swizzle
    const u16* As0 = Ahi + (size_t)(m0 + srow) * K + scol;
    const u16* Bs0 = Bhi + (size_t)(n0 + srow) * K + scol;

    f32x4 acc[FM][FN] = {};

    for (int k0 = 0; k0 < K; k0 += 64) {
        __syncthreads();                 // previous tile's compute done
#pragma unroll
        for (int q = 0; q < FM; q++)
            gload_lds16(As0 + (size_t)q * 32 * K + k0, &ldsA[q * 32 + wave * 8][0]);
#pragma unroll
        for (int q = 0; q < FN; q++)
            gload_lds16(Bs0 + (size_t)q * 32 * K + k0, &ldsB[q * 32 + wave * 8][0]);
        __syncthreads();                 // drains vmcnt(0) before barrier
#pragma unroll
        for (int ks = 0; ks < 2; ks++) {
            f16x8 ah[FM], bhf[FN];
            const int koff = ks * 64 + lk * 16;
#pragma unroll
            for (int f = 0; f < FM; f++) {
                int arow = wr + f * 16 + lr;
                int aoff = koff ^ ((arow & 7) << 4);
                ah[f] = *(const f16x8*)((const char*)(&ldsA[arow][0]) + aoff);
            }
#pragma unroll
            for (int f = 0; f < FN; f++) {
                int brow = wc + f * 16 + lr;
                int boff = koff ^ ((brow & 7) << 4);
                bhf[f] = *(const f16x8*)((const char*)(&ldsB[brow][0]) + boff);
            }
#pragma unroll
            for (int mf = 0; mf < FM; mf++)
#pragma unroll
                for (int nf = 0; nf < FN; nf++)
                    acc[mf][nf] = __builtin_amdgcn_mfma_f32_16x16x32_f16(ah[mf], bhf[nf], acc[mf][nf], 0, 0, 0);
        }
    }

    // ---- epilogue ----
#pragma unroll
    for (int mf = 0; mf < FM; mf++) {
#pragma unroll
        for (int nf = 0; nf < FN; nf++) {
            int col = n0 + wc + nf * 16 + lr;
            float bv = bias[col];
            float cv[4];
            int t0 = m0 + wr + mf * 16 + lk * 4;
#pragma unroll
            for (int r = 0; r < 4; r++) {
                float c = acc[mf][nf][r] + bv;
                if (flags & F_GELU) c = 0.5f * c * (1.0f + erff(c * 0.7071067811865476f));
                if (flags & F_RES)  c += res[(size_t)(t0 + r) * N + col];
                cv[r] = c;
            }
            if (flags & F_QKV) {
                // col -> (section, head, dh); row -> (b, t)
                int sect = col >> 9, hh = (col >> 6) & 7, dh = col & 63;
                int bb = t0 >> 11, tt = t0 & 2047;
                size_t bh = (size_t)bb * 8 + hh;
                if (sect == 2) {         // V hi, transposed: [bh][64][t]
                    ushort4 h4;
                    h4.x = f16hi(cv[0]); h4.y = f16hi(cv[1]);
                    h4.z = f16hi(cv[2]); h4.w = f16hi(cv[3]);
                    size_t vi = (bh * 64 + dh) * T_ + tt;
                    *(ushort4*)(qkvp + 2 * (size_t)PL_ + vi) = h4;
                } else {                 // Q hi (plane 0) or K hi (plane 1)
                    u16* dst = qkvp + (size_t)sect * PL_;
#pragma unroll
                    for (int r = 0; r < 4; r++) {
                        size_t qi = (bh * T_ + tt + r) * 64 + dh;
                        dst[qi] = f16hi(cv[r]);
                    }
                }
            } else if (flags & F_HI) {
#pragma unroll
                for (int r = 0; r < 4; r++)
                    Chi[(size_t)(t0 + r) * N + col] = f16hi(cv[r]);
            } else {
#pragma unroll
                for (int r = 0; r < 4; r++)
                    C[(size_t)(t0 + r) * N + col] = cv[r];
            }
        }
    }
}

// ---------------------------------------------------------------------------
// MFMA causal flash attention, fp16 1-pass, QUAD K/V staging (round-16):
// stage FOUR 64-key tiles per barrier pair (LDS 80 KB: Q + K[4] + V[4] + P,
// 2 blocks/CU = grid-limited residency anyway). Barrier pairs per block
// halve again (<=8 vs round-13's <=16); each vmcnt drain is amortized over
// 4x the MFMA work. Compute body unchanged (bit-identical math).
// Block = (qt, bh); 4 waves, wave w owns q rows [w*16, +16) x all 64 keys.
// Balanced mapping: ids u and u+256 get complementary qt (i, 31-i).
// ---------------------------------------------------------------------------
__global__ __launch_bounds__(256)
void flash_mfma_kernel(const u16* __restrict__ qkvp, u16* __restrict__ ohi) {
    const u16* qhp = qkvp;
    const u16* khp = qkvp + (size_t)PL_;
    const u16* vhp = qkvp + 2 * (size_t)PL_;

    __shared__ __align__(16) u16 Qs[64][64];
    __shared__ __align__(16) u16 Ks[4][64][64];   // [subtile][key][dh]
    __shared__ __align__(16) u16 Vs[4][64][64];   // [subtile][dh][key]
    __shared__ __align__(16) u16 Ps[64][64];

    // balanced (qt, bh) from flat id: u and u+256 -> (i, 31-i)
    const int u    = blockIdx.x;       // 0..511
    const int r0   = u & 255;
    const int bh   = r0 & 15;          // b*H + head
    const int i0   = r0 >> 4;          // 0..15
    const int qt   = (u >> 8) ? (31 - i0) : i0;

    const int tid = threadIdx.x;
    const int w = tid >> 6, lane = tid & 63;
    const int lr = lane & 15, lk = lane >> 4;

    const int srow = w * 8 + (lane >> 3);
    const int scol = ((lane & 7) ^ (lane >> 3)) * 8;

    // stage Q once (drained by first loop barrier pair)
    {
        size_t qb = ((size_t)bh * T_ + qt * 64 + srow) * 64 + scol;
#pragma unroll
        for (int q = 0; q < 2; q++)
            gload_lds16(qhp + qb + (size_t)q * 32 * 64, &Qs[q * 32 + w * 8][0]);
    }

    f32x4 accO[4] = {};
    float lsum[4] = {0.f, 0.f, 0.f, 0.f};

    auto stageKV = [&](int kt, int s) {
        size_t kb = ((size_t)bh * T_ + kt * 64 + srow) * 64 + scol;
        size_t vb = ((size_t)bh * 64 + srow) * T_ + (size_t)kt * 64 + scol;
#pragma unroll
        for (int q = 0; q < 2; q++) {
            gload_lds16(khp + kb + (size_t)q * 32 * 64, &Ks[s][q * 32 + w * 8][0]);
            gload_lds16(vhp + vb + (size_t)q * 32 * T_, &Vs[s][q * 32 + w * 8][0]);
        }
    };

    auto compute = [&](int kt, int s) {
        // ---- S = Q K^T, 1-pass: wave rows [w*16, +16), all 64 keys ----
        f32x4 accS[4] = {};
#pragma unroll
        for (int ks = 0; ks < 2; ks++) {
            const int koff = ks * 64 + lk * 16;
            const int arow = w * 16 + lr;
            const int aoff = koff ^ ((arow & 7) << 4);
            f16x8 qh = *(const f16x8*)((const char*)(&Qs[arow][0]) + aoff);
#pragma unroll
            for (int nf = 0; nf < 4; nf++) {
                int brow = nf * 16 + lr;
                int boff = koff ^ ((brow & 7) << 4);
                f16x8 kh = *(const f16x8*)((const char*)(&Ks[s][brow][0]) + boff);
                accS[nf] = __builtin_amdgcn_mfma_f32_16x16x32_f16(qh, kh, accS[nf], 0, 0, 0);
            }
        }

        // ---- mask + exp + P->fp16 LDS + row-sum partials ----
        const bool edge = (kt == qt);
#pragma unroll
        for (int nf = 0; nf < 4; nf++) {
            int keyl = nf * 16 + lr;
#pragma unroll
            for (int r = 0; r < 4; r++) {
                int rowl = lk * 4 + r;             // within wave's 16 rows
                float sv = accS[nf][r] * 0.125f;
                float p = (!edge || keyl <= w * 16 + rowl) ? __expf(sv) : 0.f;
                lsum[r] += p;
                int row = w * 16 + rowl;
                *(u16*)((char*)(&Ps[0][0]) + row * 128 + ((keyl * 2) ^ ((row & 7) << 4))) = f16hi(p);
            }
        }

        // ---- O += P V_hi (1-pass). P rows are same-wave (lgkm orders). ----
#pragma unroll
        for (int kk = 0; kk < 2; kk++) {
            const int koff = kk * 64 + lk * 16;
            const int arow = w * 16 + lr;
            f16x8 pa = *(const f16x8*)((const char*)(&Ps[0][0]) + arow * 128
                                       + (koff ^ ((arow & 7) << 4)));
#pragma unroll
            for (int nf = 0; nf < 4; nf++) {
                int brow = nf * 16 + lr;
                int boff = koff ^ ((brow & 7) << 4);
                f16x8 vh = *(const f16x8*)((const char*)(&Vs[s][brow][0]) + boff);
                accO[nf] = __builtin_amdgcn_mfma_f32_16x16x32_f16(pa, vh, accO[nf], 0, 0, 0);
            }
        }
    };

    for (int ktp = 0; ktp <= qt; ktp += 4) {
        const int nsub = (qt + 1 - ktp < 4) ? (qt + 1 - ktp) : 4;
        __syncthreads();               // all waves done reading prev K/V
        for (int s = 0; s < nsub; s++) stageKV(ktp + s, s);
        __syncthreads();               // staging drained (vmcnt 0)
        for (int s = 0; s < nsub; s++) compute(ktp + s, s);
    }

    // ---- finish: reduce row sums over the 16-lane col group, write O ----
#pragma unroll
    for (int r = 0; r < 4; r++) {
        float v = lsum[r];
        v += __shfl_xor(v, 1, 64); v += __shfl_xor(v, 2, 64);
        v += __shfl_xor(v, 4, 64); v += __shfl_xor(v, 8, 64);
        lsum[r] = v;
    }
    const int b = bh >> 3, hd = bh & 7;
#pragma unroll
    for (int nf = 0; nf < 4; nf++) {
#pragma unroll
        for (int r = 0; r < 4; r++) {
            float val = accO[nf][r] / lsum[r];
            size_t idx = ((size_t)(b * T_ + qt * 64 + w * 16 + lk * 4 + r)) * D_
                         + hd * 64 + nf * 16 + lr;
            ohi[idx] = f16hi(val);
        }
    }
}

// ---------------------------------------------------------------------------
extern "C" void kernel_launch(void* const* d_in, const int* in_sizes, int n_in,
                              void* d_out, int out_size, void* d_ws, size_t ws_size,
                              hipStream_t stream) {
    const int*   x    = (const int*)   d_in[0];
    const float* emb  = (const float*) d_in[1];
    const float* ln1s = (const float*) d_in[2];
    const float* ln1b = (const float*) d_in[3];
    const float* qkvw = (const float*) d_in[4];
    const float* qkvb = (const float*) d_in[5];
    const float* afw  = (const float*) d_in[6];
    const float* afb  = (const float*) d_in[7];
    const float* ln2s = (const float*) d_in[8];
    const float* ln2b = (const float*) d_in[9];
    const float* fw1  = (const float*) d_in[10];
    const float* fb1  = (const float*) d_in[11];
    const float* fw2  = (const float*) d_in[12];
    const float* fb2  = (const float*) d_in[13];
    const float* lnfs = (const float*) d_in[14];
    const float* lnfb = (const float*) d_in[15];
    const float* fcw  = (const float*) d_in[16];
    const float* fcb  = (const float*) d_in[17];
    float* out = (float*)d_out;

    // Workspace (~85 MB):
    //  h fp32 | yhi | atthi | qkvp 3 planes (Qhi,Khi,VThi) | ffhi |
    //  Whi per-layer slot | WhiF fc plane.
    float* h     = (float*)d_ws;
    u16*   yhi   = (u16*)(h + (size_t)M_ * D_);
    u16*   atthi = yhi   + (size_t)M_ * D_;
    u16*   qkvp  = atthi + (size_t)M_ * D_;     // 3 * PL_ u16
    u16*   ffhi  = qkvp  + 3 * (size_t)PL_;
    u16*   Whi   = ffhi  + (size_t)M_ * FF_;
    u16*   WhiF  = Whi   + WL_;

    // per-layer offsets inside the weight slot (elements)
    const size_t oq = 0, oa = 786432, of1 = 1048576, of2 = 2097152;

    embed_pe_kernel<<<M_, 128, 0, stream>>>(x, emb, h);

    for (int l = 0; l < L_; l++) {
        transpose_split4_kernel<<<3072, 256, 0, stream>>>(
            qkvw + (size_t)l * D_ * 3 * D_, afw + (size_t)l * D_ * D_,
            fw1 + (size_t)l * D_ * FF_, fw2 + (size_t)l * FF_ * D_, Whi);

        layernorm_kernel<<<M_ / 8, 512, 0, stream>>>(h, ln1s + l * D_, ln1b + l * D_, yhi);
        // qkv: N=1536, 64^2 tiles -> 1536 blocks (6/CU), F_QKV output
        mfma_gemm_t<2, 2><<<dim3(3 * D_ / 64, M_ / 64), 256, 0, stream>>>(
            yhi, Whi + oq, qkvb + l * 3 * D_,
            nullptr, nullptr, nullptr, qkvp, 3 * D_, D_, F_QKV);
        // flash: 1-D grid, balanced (qt,bh) pairing, quad staging
        flash_mfma_kernel<<<(T_ / 64) * B_ * H_, 256, 0, stream>>>(qkvp, atthi);
        // attn-fc: 32x64 tiles -> 1024 blocks (4/CU TLP), residual fp32
        mfma_gemm_t<1, 2><<<dim3(D_ / 64, M_ / 32), 256, 0, stream>>>(
            atthi, Whi + oa, afb + l * D_,
            h, h, nullptr, nullptr, D_, D_, F_RES);
        layernorm_kernel<<<M_ / 8, 512, 0, stream>>>(h, ln2s + l * D_, ln2b + l * D_, yhi);
        // ff1: 64x64 tiles -> 2048 blocks (8/CU TLP), fp16 hi out
        mfma_gemm_t<2, 2><<<dim3(FF_ / 64, M_ / 64), 256, 0, stream>>>(
            yhi, Whi + of1, fb1 + l * FF_,
            nullptr, nullptr, ffhi, nullptr, FF_, D_, F_GELU | F_HI);
        // ff2: 32x64 tiles, K=2048 -> 1024 blocks (4/CU TLP), residual fp32
        mfma_gemm_t<1, 2><<<dim3(D_ / 64, M_ / 32), 256, 0, stream>>>(
            ffhi, Whi + of2, fb2 + l * D_,
            h, h, nullptr, nullptr, D_, FF_, F_RES);
    }

    transpose_split_kernel<<<dim3(V_ / 32, D_ / 32), dim3(32, 8), 0, stream>>>(
        fcw, WhiF, D_, V_);
    layernorm_kernel<<<M_ / 8, 512, 0, stream>>>(h, lnfs, lnfb, yhi);
    // vocab: 128^2 tiles, F_XCDM mapping (compute-bound, unchanged)
    mfma_gemm_t<4, 4><<<dim3(V_ / 128, M_ / 128), 256, 0, stream>>>(
        yhi, WhiF, fcb, nullptr, out, nullptr, nullptr, V_, D_, F_XCDM);
}